// Round 8
// baseline (12193.118 us; speedup 1.0000x reference)
//
#include <hip/hip_runtime.h>
#include <cstdint>
#include <cstddef>

#define T_ 512
#define B_ 32
#define D_ 1024
#define L_ 4
#define BD_ (B_*D_)
#define TPB 256
#define NWG 256
#define EPSF 1e-5f

typedef _Float16 f16x8 __attribute__((ext_vector_type(8)));
typedef float f32x4 __attribute__((ext_vector_type(4)));
typedef float f32x2 __attribute__((ext_vector_type(2)));
typedef unsigned int u32x4 __attribute__((ext_vector_type(4)));
typedef unsigned long long u64;

// workspace layout (bytes)
#define WSO_ROOT   0
#define WSO_GRP    64
#define WSO_HSTAT  4096
#define WSO_YSTAT  7168
#define WSO_XSTAT  8192
#define WSO_ST16   139264
#define WSO_H16    663552
#define WSO_WT     2097152

// LDS layout (bytes)
#define LDS_W     0        // 32 cols x 2048 fused-k fp16, col stride 4096, XOR-swizzled
#define LDS_DUMP  131072   // 16 tiles x 64 lanes x 16B = 16384
#define LDS_GB    147456   // li0: f32 g[1024]|b[1024] (8KB); li>0: u32 gpk[512]|bpk[512] (4KB)
#define LDS_NS    155904   // 32 rows x 80B (20 floats, 16B-aligned stride)
#define LDS_BIAS  158464   // 32 f32 (bf|bc)
#define LDS_SGSB  158592   // 32 f32 (sg|sb)
#define LDS_TOTAL 158720
#define NSTR 20

__device__ __forceinline__ unsigned pk2h(float a, float b){
  _Float16 ha=(_Float16)a, hb=(_Float16)b;
  return (unsigned)__builtin_bit_cast(unsigned short,ha) |
         ((unsigned)__builtin_bit_cast(unsigned short,hb)<<16);
}
__device__ __forceinline__ float cload1(const float* p){
  unsigned v=__hip_atomic_load((const unsigned*)(const void*)p,__ATOMIC_RELAXED,__HIP_MEMORY_SCOPE_AGENT);
  return __builtin_bit_cast(float,v);
}
__device__ __forceinline__ void cstore1(float* p, float v){
  __hip_atomic_store((unsigned*)(void*)p,__builtin_bit_cast(unsigned,v),__ATOMIC_RELAXED,__HIP_MEMORY_SCOPE_AGENT);
}
// 16B coherent store as 2 x u64 relaxed agent-scope atomic stores (write-through to L3)
__device__ __forceinline__ void cstore16(unsigned short* p, unsigned w0, unsigned w1, unsigned w2, unsigned w3){
  u64 lo=((u64)w1<<32)|w0, hi=((u64)w3<<32)|w2;
  __hip_atomic_store((u64*)(void*)p,     lo, __ATOMIC_RELAXED, __HIP_MEMORY_SCOPE_AGENT);
  __hip_atomic_store((u64*)(void*)(p+4), hi, __ATOMIC_RELAXED, __HIP_MEMORY_SCOPE_AGENT);
}

#define GLD(d,vo,sb) asm volatile("global_load_dwordx4 %0, %1, %2" : "=v"(d) : "v"(vo), "s"(sb) : "memory")
#define WAITV(N) do{ asm volatile("s_waitcnt vmcnt(" #N ")" ::: "memory"); __builtin_amdgcn_sched_barrier(0); }while(0)
#define BARS do{ asm volatile("s_waitcnt lgkmcnt(0)" ::: "memory"); __builtin_amdgcn_s_barrier(); }while(0)

// per-chunk A loads: chunks 0-7 = h (LN applied at use), 8-15 = state (raw). ALL cached (L2-shared per XCD).
#define LOADC(c) do{ const int s_=(c)&3; \
  if (ISX){ \
    if ((c)<8){ \
      GLD(pay[s_][0][0], vxA+(c)*512,    sbH); GLD(pay[s_][0][1], vxA+(c)*512+16, sbH); \
      GLD(pay[s_][1][0], vxB+(c)*512,    sbH); GLD(pay[s_][1][1], vxB+(c)*512+16, sbH); \
    } else { \
      GLD(pay[s_][0][0], voA+((c)-8)*256, sbS); GLD(pay[s_][1][0], voB+((c)-8)*256, sbS); \
    } \
  } else { \
    if ((c)<8){ GLD(pay[s_][0][0], voA+(c)*256, sbH); GLD(pay[s_][1][0], voB+(c)*256, sbH); } \
    else      { GLD(pay[s_][0][0], voA+((c)-8)*256, sbS); GLD(pay[s_][1][0], voB+((c)-8)*256, sbS); } \
  } \
}while(0)

#define PROC(c) do{ const int s_=(c)&3; f16x8 a0,a1; \
    const int kf_=(c)*128+kq; \
    if ((c)<8){ \
      if (ISX){ \
        f32x4 xa0=__builtin_bit_cast(f32x4,pay[s_][0][0]), xa1=__builtin_bit_cast(f32x4,pay[s_][0][1]); \
        f32x4 xb0=__builtin_bit_cast(f32x4,pay[s_][1][0]), xb1=__builtin_bit_cast(f32x4,pay[s_][1][1]); \
        f32x4 g0=*(const f32x4*)(GBg32+kf_), g1=*(const f32x4*)(GBg32+kf_+4); \
        f32x4 q0=*(const f32x4*)(GBg32+1024+kf_), q1=*(const f32x4*)(GBg32+1024+kf_+4); \
        a0[0]=(_Float16)((xa0[0]*rsA+nmA)*g0[0]+q0[0]); a0[1]=(_Float16)((xa0[1]*rsA+nmA)*g0[1]+q0[1]); \
        a0[2]=(_Float16)((xa0[2]*rsA+nmA)*g0[2]+q0[2]); a0[3]=(_Float16)((xa0[3]*rsA+nmA)*g0[3]+q0[3]); \
        a0[4]=(_Float16)((xa1[0]*rsA+nmA)*g1[0]+q1[0]); a0[5]=(_Float16)((xa1[1]*rsA+nmA)*g1[1]+q1[1]); \
        a0[6]=(_Float16)((xa1[2]*rsA+nmA)*g1[2]+q1[2]); a0[7]=(_Float16)((xa1[3]*rsA+nmA)*g1[3]+q1[3]); \
        a1[0]=(_Float16)((xb0[0]*rsB+nmB)*g0[0]+q0[0]); a1[1]=(_Float16)((xb0[1]*rsB+nmB)*g0[1]+q0[1]); \
        a1[2]=(_Float16)((xb0[2]*rsB+nmB)*g0[2]+q0[2]); a1[3]=(_Float16)((xb0[3]*rsB+nmB)*g0[3]+q0[3]); \
        a1[4]=(_Float16)((xb1[0]*rsB+nmB)*g1[0]+q1[0]); a1[5]=(_Float16)((xb1[1]*rsB+nmB)*g1[1]+q1[1]); \
        a1[6]=(_Float16)((xb1[2]*rsB+nmB)*g1[2]+q1[2]); a1[7]=(_Float16)((xb1[3]*rsB+nmB)*g1[3]+q1[3]); \
      } else { \
        f16x8 g8=*(const f16x8*)(GBg16+(kf_>>1)); \
        f16x8 b8=*(const f16x8*)(GBg16+512+(kf_>>1)); \
        a0=__builtin_bit_cast(f16x8,pay[s_][0][0]); a1=__builtin_bit_cast(f16x8,pay[s_][1][0]); \
        a0=a0*rsA8+nmA8; a0=a0*g8+b8; \
        a1=a1*rsB8+nmB8; a1=a1*g8+b8; \
      } \
    } else { \
      a0=__builtin_bit_cast(f16x8,pay[s_][0][0]); a1=__builtin_bit_cast(f16x8,pay[s_][1][0]); \
    } \
    const int kb_=kf_*2; \
    f16x8 bF=*(const f16x8*)(WF + (kb_^swl)); \
    f16x8 bC=*(const f16x8*)(WC + (kb_^swl)); \
    accF0=__builtin_amdgcn_mfma_f32_16x16x32_f16(a0,bF,accF0,0,0,0); \
    accF1=__builtin_amdgcn_mfma_f32_16x16x32_f16(a1,bF,accF1,0,0,0); \
    accC0=__builtin_amdgcn_mfma_f32_16x16x32_f16(a0,bC,accC0,0,0,0); \
    accC1=__builtin_amdgcn_mfma_f32_16x16x32_f16(a1,bC,accC1,0,0,0); \
  }while(0)

#define CH(c,NW) do{ if ((c)<13) LOADC((c)+3); WAITV(NW); PROC(c); }while(0)

template<int ISX>
__device__ __forceinline__ void stage_pre(u32x4 (&pay)[4][2][2],
    u64 sbH, u64 sbS, int voA, int voB, int vxA, int vxB)
{
  LOADC(0); LOADC(1); LOADC(2);
}

template<int ISX>
__device__ __forceinline__ void chunk_run(char* smem, u32x4 (&pay)[4][2][2],
    u64 sbH, u64 sbS, int voA, int voB, int vxA, int vxB,
    int l15, int kq, float2 mrA, float2 mrB,
    f32x4& accF0, f32x4& accF1, f32x4& accC0, f32x4& accC1)
{
  const char* WF = smem + LDS_W + l15*4096;
  const char* WC = smem + LDS_W + (16+l15)*4096;
  const int swl = (l15&7)<<4;
  const float rsA = mrA.y, rsB = mrB.y;
  const float nmA = -mrA.x*rsA, nmB = -mrB.x*rsB;
  const _Float16 hrA=(_Float16)rsA, hmA=(_Float16)nmA, hrB=(_Float16)rsB, hmB=(_Float16)nmB;
  const f16x8 rsA8={hrA,hrA,hrA,hrA,hrA,hrA,hrA,hrA};
  const f16x8 nmA8={hmA,hmA,hmA,hmA,hmA,hmA,hmA,hmA};
  const f16x8 rsB8={hrB,hrB,hrB,hrB,hrB,hrB,hrB,hrB};
  const f16x8 nmB8={hmB,hmB,hmB,hmB,hmB,hmB,hmB,hmB};
  const unsigned* GBg16 = (const unsigned*)(smem+LDS_GB);
  const float* GBg32 = (const float*)(smem+LDS_GB);

  if (ISX){
    CH(0,12);CH(1,12);CH(2,12);CH(3,12);CH(4,12);CH(5,10);CH(6,8);CH(7,6);
    CH(8,6);CH(9,6);CH(10,6);CH(11,6);CH(12,6);CH(13,4);CH(14,2);CH(15,0);
  } else {
    CH(0,6);CH(1,6);CH(2,6);CH(3,6);CH(4,6);CH(5,6);CH(6,6);CH(7,6);
    CH(8,6);CH(9,6);CH(10,6);CH(11,6);CH(12,6);CH(13,4);CH(14,2);CH(15,0);
  }
}

// ---------------- pre-pass 1: fp32 (D,D) row-major -> fp16 transposed fused layout ----------------
extern "C" __global__ void __launch_bounds__(256,1) crs_prepass(
    const float* __restrict__ Wf, const float* __restrict__ Uf,
    const float* __restrict__ Wc, const float* __restrict__ Uc,
    unsigned short* __restrict__ WT)
{
  int bid = blockIdx.x;
  int kt  = bid & 15;
  int ct  = (bid>>4) & 31;
  int sel = (bid>>9) & 3;
  int i   = bid >> 11;
  int tid = threadIdx.x;
  int kq  = tid >> 5;
  int cc  = tid & 31;
  const float* sp;
  if      (sel==0) sp = Wf;
  else if (sel==1) sp = Uf;
  else if (sel==2) sp = Wc;
  else             sp = Uc;
  sp += (size_t)i * 1048576;
  int cl = ct*32 + cc;
  int k0 = kt*64 + kq*8;
  float f[8];
  #pragma unroll
  for (int e=0;e<8;++e){ f[e] = sp[(size_t)(k0+e)*1024 + cl]; }
  int cg = ((sel>>1) ? 1024 : 0) + cl;
  int ks = sel & 1;
  size_t idx = ((size_t)(i*2048 + cg)*2 + ks)*1024 + k0;
  uint4 pk;
  pk.x = pk2h(f[0], f[1]);
  pk.y = pk2h(f[2], f[3]);
  pk.z = pk2h(f[4], f[5]);
  pk.w = pk2h(f[6], f[7]);
  *(uint4*)(WT + idx) = pk;
}

// ---------------- pre-pass 2: x row-stats + initial state -> fp16 ----------------
extern "C" __global__ void __launch_bounds__(256,1) crs_prep2(
    const float* __restrict__ x, const float* __restrict__ st0,
    float* __restrict__ xstat, unsigned short* __restrict__ st16)
{
  __shared__ float2 part[256];
  int bid=blockIdx.x, tid=threadIdx.x;
  int rr=tid>>3, ss=tid&7;
  if (bid<T_){
    const float4* p4=(const float4*)(x+(size_t)bid*BD_+rr*1024+ss*128);
    float s1=0.f,s2=0.f;
    #pragma unroll 8
    for (int q=0;q<32;++q){ float4 a=p4[q]; s1+=a.x+a.y+a.z+a.w; s2+=a.x*a.x+a.y*a.y+a.z*a.z+a.w*a.w; }
    part[tid]=make_float2(s1,s2);
    __syncthreads();
    if (tid<32){
      float a1=0.f,a2=0.f;
      #pragma unroll
      for (int e=0;e<8;++e){ float2 pp=part[tid*8+e]; a1+=pp.x; a2+=pp.y; }
      xstat[bid*64+tid*2]=a1; xstat[bid*64+tid*2+1]=a2;
    }
  } else {
    int i2=bid-T_;
    const float4* p4=(const float4*)(st0+(size_t)i2*BD_+rr*1024+ss*128);
    uint4* dst=(uint4*)(st16+((size_t)i2*2)*32768+rr*1024+ss*128);
    #pragma unroll
    for (int q=0;q<16;++q){
      float4 a=p4[2*q], b=p4[2*q+1];
      uint4 pk; pk.x=pk2h(a.x,a.y); pk.y=pk2h(a.z,a.w); pk.z=pk2h(b.x,b.y); pk.w=pk2h(b.z,b.w);
      dst[q]=pk;
    }
  }
}

// ---------------- main persistent kernel ----------------
extern "C" __global__ void __launch_bounds__(TPB,1) crs_main(
    const float* __restrict__ x, const float* __restrict__ st0,
    const float* __restrict__ bfv, const float* __restrict__ bcv,
    const float* __restrict__ pg, const float* __restrict__ pb,
    const float* __restrict__ sg, const float* __restrict__ sbv,
    float* __restrict__ y, float* __restrict__ ostate,
    const unsigned short* __restrict__ WT, char* __restrict__ ws)
{
  extern __shared__ char smem[];
  const int tid=threadIdx.x, w=blockIdx.x;
  const int li=w>>6, wr=w&63;
  const int lane=tid&63, v=tid>>6;        // v = k-quarter
  const int l15=lane&15, lg=(lane>>4)&3;
  const int kq = v*32 + lg*8;             // fused-k element offset within a 128-chunk
  const int col=lane&15, rp=lane>>4;      // epilogue mapping
  const int r0=v*8+rp, r1=v*8+4+rp;
  const int sseg=tid&7;

  unsigned* root=(unsigned*)(ws+WSO_ROOT);
  unsigned* grpc=(unsigned*)(ws+WSO_GRP)+(w>>5)*64;
  float* hstat=(float*)(ws+WSO_HSTAT);
  float* ystat=(float*)(ws+WSO_YSTAT);
  float* xstat=(float*)(ws+WSO_XSTAT);
  unsigned short* st16=(unsigned short*)(ws+WSO_ST16);
  unsigned short* h16=(unsigned short*)(ws+WSO_H16);
  float* NSf=(float*)(smem+LDS_NS);
  float* BIAS=(float*)(smem+LDS_BIAS);
  float* SGSB=(float*)(smem+LDS_SGSB);

  // ---- one-time init: weights -> LDS (swizzled)
  {
    int lc=tid>>3;
    int cgl=(lc>>4)*1024 + wr*16 + (lc&15);
    const unsigned short* src=WT + ((size_t)li*2048+cgl)*2048;
    char* dcol = smem + LDS_W + lc*4096;
    int sw2=(lc&7)<<4;
    #pragma unroll
    for (int n=0;n<32;++n){
      int q=sseg+n*8;
      uint4 d=*(const uint4*)(src+q*8);
      *(uint4*)(dcol + ((q*16)^sw2)) = d;
    }
  }
  if (li==0){
    float* g32=(float*)(smem+LDS_GB);
    for (int k=tid;k<1024;k+=TPB){ g32[k]=pg[k]; g32[1024+k]=pb[k]; }
  } else {
    unsigned* g16=(unsigned*)(smem+LDS_GB);
    for (int k=tid;k<512;k+=TPB){
      g16[k]    =pk2h(pg[li*1024+2*k], pg[li*1024+2*k+1]);
      g16[512+k]=pk2h(pb[li*1024+2*k], pb[li*1024+2*k+1]);
    }
  }
  if (tid<16) BIAS[tid]=bfv[li*1024+wr*16+tid];
  else if (tid<32) BIAS[tid]=bcv[li*1024+wr*16+(tid-16)];
  if (li==3){
    if (tid<16) SGSB[tid]=sg[wr*16+tid];
    else if (tid<32) SGSB[tid]=sbv[wr*16+(tid-16)];
  }
  f32x2 sreg, pns={0.f,0.f};
  sreg.x = st0[(size_t)li*BD_ + (size_t)r0*D_ + wr*16+col];
  sreg.y = st0[(size_t)li*BD_ + (size_t)r1*D_ + wr*16+col];
  __syncthreads();

  for (int p=0;p<T_+L_-1;++p){
    int t=p-li;
    if (t>=0 && t<T_){
      // ---- per-lane LN stats for A rows l15 / 16+l15 (only compiler vm-ops before asm stream)
      float2 mrA, mrB;
      {
        float s1,s2,s3,s4;
        if (li==0){
          const float* xs=xstat+t*64;
          s1=xs[l15*2]; s2=xs[l15*2+1]; s3=xs[(16+l15)*2]; s4=xs[(16+l15)*2+1];
        } else {
          const float* hs=hstat+((li-1)*4+(t&3))*64;
          s1=cload1(hs+l15*2);      s2=cload1(hs+l15*2+1);
          s3=cload1(hs+(16+l15)*2); s4=cload1(hs+(16+l15)*2+1);
        }
        float m=s1*(1.f/1024.f);
        mrA=make_float2(m, rsqrtf(s2*(1.f/1024.f)-m*m+EPSF));
        float m2=s3*(1.f/1024.f);
        mrB=make_float2(m2, rsqrtf(s4*(1.f/1024.f)-m2*m2+EPSF));
        // pin: force stat values materialized before the asm prefetch stream
        asm volatile("" : "+v"(mrA.x), "+v"(mrA.y), "+v"(mrB.x), "+v"(mrB.y));
      }

      const unsigned short* h16b = (li>0)? (h16 + ((size_t)(li-1)*2+(size_t)(t&1))*32768) : (const unsigned short*)0;
      u64 sbH = (li==0)? (u64)(uintptr_t)(x + (size_t)t*BD_) : (u64)(uintptr_t)h16b;
      u64 sbS = (u64)(uintptr_t)(st16 + ((size_t)li*2+(size_t)(t&1))*32768);
      const int voA = l15*2048 + kq*2, voB = voA + 32768;
      const int vxA = l15*4096 + kq*4, vxB = vxA + 65536;
      u32x4 pay[4][2][2];
      if (li==0) stage_pre<1>(pay, sbH, sbS, voA, voB, vxA, vxB);
      else       stage_pre<0>(pay, sbH, sbS, voA, voB, vxA, vxB);

      f32x4 accF0={0,0,0,0}, accF1={0,0,0,0}, accC0={0,0,0,0}, accC1={0,0,0,0};
      if (li==0) chunk_run<1>(smem, pay, sbH, sbS, voA, voB, vxA, vxB, l15, kq, mrA, mrB, accF0, accF1, accC0, accC1);
      else       chunk_run<0>(smem, pay, sbH, sbS, voA, voB, vxA, vxB, l15, kq, mrA, mrB, accF0, accF1, accC0, accC1);

      *(f32x4*)(smem+LDS_DUMP + (((v*4+0)*64+lane)<<4)) = accF0;
      *(f32x4*)(smem+LDS_DUMP + (((v*4+1)*64+lane)<<4)) = accF1;
      *(f32x4*)(smem+LDS_DUMP + (((v*4+2)*64+lane)<<4)) = accC0;
      *(f32x4*)(smem+LDS_DUMP + (((v*4+3)*64+lane)<<4)) = accC1;
      BARS;

      f32x2 pns_prev = pns;   // li==3: previous timestep's state (for y[t-1] below)
      {
        const int rtl = v>>1;
        const int lg20 = (v&1)*2, lg21 = (v&1)*2+1;
        float fF0=0.f,fF1=0.f,fC0=0.f,fC1=0.f;
        #pragma unroll
        for (int v2=0;v2<4;++v2){
          const char* db = smem+LDS_DUMP + v2*4096;
          fF0 += *(const float*)(db + (((0+rtl)*64 + lg20*16+col)<<4) + rp*4);
          fF1 += *(const float*)(db + (((0+rtl)*64 + lg21*16+col)<<4) + rp*4);
          fC0 += *(const float*)(db + (((2+rtl)*64 + lg20*16+col)<<4) + rp*4);
          fC1 += *(const float*)(db + (((2+rtl)*64 + lg21*16+col)<<4) + rp*4);
        }
        float bfc=BIAS[col], bcc=BIAS[16+col];
        float preF0=fminf(fmaxf(fF0+bfc,-30.f),30.f);
        float preC0=fminf(fmaxf(fC0+bcc,-30.f),30.f);
        float preF1=fminf(fmaxf(fF1+bfc,-30.f),30.f);
        float preC1=fminf(fmaxf(fC1+bcc,-30.f),30.f);
        float fg0=1.f/(1.f+__expf(-preF0)), e0=__expf(-2.f*preC0);
        float cd0=(1.f-e0)/(1.f+e0);
        float fg1=1.f/(1.f+__expf(-preF1)), e1=__expf(-2.f*preC1);
        float cd1=(1.f-e1)/(1.f+e1);
        float ns0=fg0*sreg.x+(1.f-fg0)*cd0;
        float ns1=fg1*sreg.y+(1.f-fg1)*cd1;
        sreg.x=ns0; sreg.y=ns1;
        if (li==3){ pns.x=ns0; pns.y=ns1; }
        float a1=ns0, a2=ns0*ns0, a3=ns1, a4=ns1*ns1;
        #pragma unroll
        for (int m=1;m<16;m<<=1){
          a1+=__shfl_xor(a1,m); a2+=__shfl_xor(a2,m);
          a3+=__shfl_xor(a3,m); a4+=__shfl_xor(a4,m);
        }
        float* stadd=(li<3)? (hstat+(li*4+(t&3))*64) : (ystat+(t&3)*64);
        if (col==0){
          atomicAdd(stadd+r0*2,   a1); atomicAdd(stadd+r0*2+1, a2);
          atomicAdd(stadd+r1*2,   a3); atomicAdd(stadd+r1*2+1, a4);
        }
        NSf[r0*NSTR+col]=ns0;
        NSf[r1*NSTR+col]=ns1;
      }
      // pack + coherent stores (same-wave NSf reuse; compiler inserts lgkmcnt waits)
      if (lane<16){
        int row = v*8 + (lane>>1), hf = lane&1;
        const float* nr = NSf + row*NSTR + hf*8;
        f32x4 q0 = *(const f32x4*)nr, q1 = *(const f32x4*)(nr+4);
        unsigned w0=pk2h(q0[0],q0[1]), w1=pk2h(q0[2],q0[3]);
        unsigned w2=pk2h(q1[0],q1[1]), w3=pk2h(q1[2],q1[3]);
        unsigned short* sd = st16 + ((size_t)li*2+(size_t)((t+1)&1))*32768 + row*1024 + wr*16 + hf*8;
        cstore16(sd, w0, w1, w2, w3);
        if (li<3){
          unsigned short* hd = h16 + ((size_t)li*2+(size_t)(t&1))*32768 + row*1024 + wr*16 + hf*8;
          cstore16(hd, w0, w1, w2, w3);
        }
        if (t==T_-1){
          float* op = ostate + (size_t)li*BD_ + (size_t)row*D_ + wr*16 + hf*8;
          *(f32x4*)op = q0; *(f32x4*)(op+4) = q1;
        }
      }
      // ---- moved tail-matter: y[t-1] (li3, uses pns_prev + completed ystat slot) + ring-zero
      if (li==3 && t>=1){
        const float* stY=ystat+((t-1)&3)*64;
        float gv=SGSB[col], bv=SGSB[16+col];
        float s1=cload1(stY+r0*2), s2=cload1(stY+r0*2+1);
        float m0=s1*(1.f/1024.f);
        float rs0=rsqrtf(s2*(1.f/1024.f)-m0*m0+EPSF);
        y[(size_t)(t-1)*BD_+(size_t)r0*D_+wr*16+col]=(pns_prev.x-m0)*rs0*gv+bv;
        float s3=cload1(stY+r1*2), s4=cload1(stY+r1*2+1);
        float m1=s3*(1.f/1024.f);
        float rs1=rsqrtf(s4*(1.f/1024.f)-m1*m1+EPSF);
        y[(size_t)(t-1)*BD_+(size_t)r1*D_+wr*16+col]=(pns_prev.y-m1)*rs1*gv+bv;
      }
      if (v==0 && wr==0 && t>=2){
        float* zp=(li<3)? (hstat+(li*4+((t-2)&3))*64) : (ystat+((t-2)&3)*64);
        cstore1(zp+tid,0.f);
      }
    }
    // ---- hierarchical fence-free grid barrier + L2 invalidate (weights safe in LDS)
    asm volatile("s_waitcnt vmcnt(0)" ::: "memory");
    __syncthreads();
    if (tid==0){
      unsigned old=__hip_atomic_fetch_add(grpc,1u,__ATOMIC_RELAXED,__HIP_MEMORY_SCOPE_AGENT);
      if (old==(unsigned)(p*32+31))
        __hip_atomic_fetch_add(root,1u,__ATOMIC_RELAXED,__HIP_MEMORY_SCOPE_AGENT);
      unsigned tgt=(unsigned)((p+1)*8);
      while (__hip_atomic_load(root,__ATOMIC_RELAXED,__HIP_MEMORY_SCOPE_AGENT)<tgt)
        __builtin_amdgcn_s_sleep(2);
    }
    __syncthreads();
    __builtin_amdgcn_fence(__ATOMIC_ACQUIRE, "agent");   // buffer_inv: drop stale L2/L1 lines
  }

  if (li==3){
    const float* stY=ystat+((T_-1)&3)*64;
    float gv=SGSB[col], bv=SGSB[16+col];
    float s1=cload1(stY+r0*2), s2=cload1(stY+r0*2+1);
    float m0=s1*(1.f/1024.f);
    float rs0=rsqrtf(s2*(1.f/1024.f)-m0*m0+EPSF);
    y[(size_t)(T_-1)*BD_+(size_t)r0*D_+wr*16+col]=(pns.x-m0)*rs0*gv+bv;
    float s3=cload1(stY+r1*2), s4=cload1(stY+r1*2+1);
    float m1=s3*(1.f/1024.f);
    float rs1=rsqrtf(s4*(1.f/1024.f)-m1*m1+EPSF);
    y[(size_t)(T_-1)*BD_+(size_t)r1*D_+wr*16+col]=(pns.y-m1)*rs1*gv+bv;
  }
}

extern "C" void kernel_launch(void* const* d_in, const int* in_sizes, int n_in,
                              void* d_out, int out_size, void* d_ws, size_t ws_size,
                              hipStream_t stream){
  (void)in_sizes; (void)n_in; (void)out_size; (void)ws_size;
  const float* x   = (const float*)d_in[0];
  const float* st0 = (const float*)d_in[1];
  const float* Wf  = (const float*)d_in[2];
  const float* Uf  = (const float*)d_in[3];
  const float* bfv = (const float*)d_in[4];
  const float* Wc  = (const float*)d_in[5];
  const float* Uc  = (const float*)d_in[6];
  const float* bcv = (const float*)d_in[7];
  const float* pg  = (const float*)d_in[8];
  const float* pb  = (const float*)d_in[9];
  const float* sg  = (const float*)d_in[10];
  const float* sbv = (const float*)d_in[11];

  float* y      = (float*)d_out;
  float* ostate = y + (size_t)T_*BD_;
  char* ws = (char*)d_ws;

  (void)hipMemsetAsync(ws, 0, 8192, stream);
  hipLaunchKernelGGL(crs_prepass, dim3(8192), dim3(256), 0, stream,
                     Wf, Uf, Wc, Uc, (unsigned short*)(ws+WSO_WT));
  hipLaunchKernelGGL(crs_prep2, dim3(T_+L_), dim3(256), 0, stream,
                     x, st0, (float*)(ws+WSO_XSTAT), (unsigned short*)(ws+WSO_ST16));
  (void)hipFuncSetAttribute((const void*)crs_main, hipFuncAttributeMaxDynamicSharedMemorySize, LDS_TOTAL);
  hipLaunchKernelGGL(crs_main, dim3(NWG), dim3(TPB), LDS_TOTAL, stream,
                     x, st0, bfv, bcv, pg, pb, sg, sbv, y, ostate,
                     (const unsigned short*)(ws+WSO_WT), ws);
}

// Round 10
// 8792.657 us; speedup vs baseline: 1.3867x; 1.3867x over previous
//
#include <hip/hip_runtime.h>
#include <cstdint>
#include <cstddef>

#define T_ 512
#define B_ 32
#define D_ 1024
#define L_ 4
#define BD_ (B_*D_)
#define TPB 256
#define NWG 256
#define EPSF 1e-5f

typedef _Float16 f16x8 __attribute__((ext_vector_type(8)));
typedef float f32x4 __attribute__((ext_vector_type(4)));
typedef float f32x2 __attribute__((ext_vector_type(2)));
typedef unsigned int u32x4 __attribute__((ext_vector_type(4)));
typedef unsigned long long u64;

// workspace layout (bytes)
#define WSO_ROOT   0
#define WSO_GRP    64
#define WSO_HSTAT  4096
#define WSO_YSTAT  7168
#define WSO_XSTAT  8192
#define WSO_ST16   139264
#define WSO_H16    663552
#define WSO_WT     2097152

// LDS layout (bytes)
#define LDS_W     0        // 32 cols x 2048 fused-k fp16, col stride 4096, XOR-swizzled
#define LDS_DUMP  131072   // 16 tiles x 64 lanes x 16B = 16384
#define LDS_GB    147456   // li0: f32 g[1024]|b[1024] (8KB); li>0: u32 gpk[512]|bpk[512] (4KB)
#define LDS_MRS   155648   // 32 float2
#define LDS_NS    155904   // 32 rows x 80B (20 floats, 16B-aligned stride)
#define LDS_BIAS  158464   // 32 f32 (bf|bc)
#define LDS_SGSB  158592   // 32 f32 (sg|sb)
#define LDS_TOTAL 158720
#define NSTR 20

__device__ __forceinline__ unsigned pk2h(float a, float b){
  _Float16 ha=(_Float16)a, hb=(_Float16)b;
  return (unsigned)__builtin_bit_cast(unsigned short,ha) |
         ((unsigned)__builtin_bit_cast(unsigned short,hb)<<16);
}
__device__ __forceinline__ float cload1(const float* p){
  unsigned v=__hip_atomic_load((const unsigned*)(const void*)p,__ATOMIC_RELAXED,__HIP_MEMORY_SCOPE_AGENT);
  return __builtin_bit_cast(float,v);
}
__device__ __forceinline__ void cstore1(float* p, float v){
  __hip_atomic_store((unsigned*)(void*)p,__builtin_bit_cast(unsigned,v),__ATOMIC_RELAXED,__HIP_MEMORY_SCOPE_AGENT);
}
// 16B coherent store as 2 x u64 relaxed agent-scope atomic stores (write-through to L3)
__device__ __forceinline__ void cstore16(unsigned short* p, unsigned w0, unsigned w1, unsigned w2, unsigned w3){
  u64 lo=((u64)w1<<32)|w0, hi=((u64)w3<<32)|w2;
  __hip_atomic_store((u64*)(void*)p,     lo, __ATOMIC_RELAXED, __HIP_MEMORY_SCOPE_AGENT);
  __hip_atomic_store((u64*)(void*)(p+4), hi, __ATOMIC_RELAXED, __HIP_MEMORY_SCOPE_AGENT);
}

#define GLD(d,vo,sb)    asm volatile("global_load_dwordx4 %0, %1, %2 sc0 sc1" : "=v"(d) : "v"(vo), "s"(sb) : "memory")
#define GLDX(d,vo,sb)   asm volatile("global_load_dwordx4 %0, %1, %2"          : "=v"(d) : "v"(vo), "s"(sb) : "memory")
#define WAITV(N) do{ asm volatile("s_waitcnt vmcnt(" #N ")" ::: "memory"); __builtin_amdgcn_sched_barrier(0); }while(0)
#define BARS do{ asm volatile("s_waitcnt lgkmcnt(0)" ::: "memory"); __builtin_amdgcn_s_barrier(); }while(0)

// slot accessors into the flat payload array
#define PN(s,h)   pay[(s)*2+(h)]          // non-ISX: 6 slots x 2
#define PX(s,h,j) pay[(s)*4+(h)*2+(j)]    // ISX:     5 slots x 4

// ---- non-ISX (li>0): 2 fp16 loads per chunk, 6 slots, depth-5
#define LOADC_N(c) do{ const int s_=(c)%6; \
  if ((c)<8){ GLD(PN(s_,0), voA+(c)*256, sbH); GLD(PN(s_,1), voB+(c)*256, sbH); } \
  else      { GLD(PN(s_,0), voA+((c)-8)*256, sbS); GLD(PN(s_,1), voB+((c)-8)*256, sbS); } \
}while(0)

#define PROC_N(c) do{ const int s_=(c)%6; f16x8 a0,a1; \
    const int kf_=(c)*128+kq; \
    if ((c)<8){ \
      f16x8 g8=*(const f16x8*)(GBg16+(kf_>>1)); \
      f16x8 b8=*(const f16x8*)(GBg16+512+(kf_>>1)); \
      a0=__builtin_bit_cast(f16x8,PN(s_,0)); a1=__builtin_bit_cast(f16x8,PN(s_,1)); \
      a0=a0*rsA8+nmA8; a0=a0*g8+b8; \
      a1=a1*rsB8+nmB8; a1=a1*g8+b8; \
    } else { \
      a0=__builtin_bit_cast(f16x8,PN(s_,0)); a1=__builtin_bit_cast(f16x8,PN(s_,1)); \
    } \
    const int kb_=kf_*2; \
    f16x8 bF=*(const f16x8*)(WF + (kb_^swl)); \
    f16x8 bC=*(const f16x8*)(WC + (kb_^swl)); \
    accF0=__builtin_amdgcn_mfma_f32_16x16x32_f16(a0,bF,accF0,0,0,0); \
    accF1=__builtin_amdgcn_mfma_f32_16x16x32_f16(a1,bF,accF1,0,0,0); \
    accC0=__builtin_amdgcn_mfma_f32_16x16x32_f16(a0,bC,accC0,0,0,0); \
    accC1=__builtin_amdgcn_mfma_f32_16x16x32_f16(a1,bC,accC1,0,0,0); \
  }while(0)

#define CHN(c,NW) do{ if ((c)<11) LOADC_N((c)+5); WAITV(NW); PROC_N(c); }while(0)

// ---- ISX (li==0): chunks 0-7 = 4 fp32-x loads (cached), 8-15 = 2 fp16 state loads; 5 slots, depth-4
#define LOADC_X(c) do{ const int s_=(c)%5; \
  if ((c)<8){ \
    GLDX(PX(s_,0,0), vxA+(c)*512,    sbH); GLDX(PX(s_,0,1), vxA+(c)*512+16, sbH); \
    GLDX(PX(s_,1,0), vxB+(c)*512,    sbH); GLDX(PX(s_,1,1), vxB+(c)*512+16, sbH); \
  } else { \
    GLD(PX(s_,0,0), voA+((c)-8)*256, sbS); GLD(PX(s_,1,0), voB+((c)-8)*256, sbS); \
  } \
}while(0)

#define PROC_X(c) do{ const int s_=(c)%5; f16x8 a0,a1; \
    const int kf_=(c)*128+kq; \
    if ((c)<8){ \
      f32x4 xa0=__builtin_bit_cast(f32x4,PX(s_,0,0)), xa1=__builtin_bit_cast(f32x4,PX(s_,0,1)); \
      f32x4 xb0=__builtin_bit_cast(f32x4,PX(s_,1,0)), xb1=__builtin_bit_cast(f32x4,PX(s_,1,1)); \
      f32x4 g0=*(const f32x4*)(GBg32+kf_), g1=*(const f32x4*)(GBg32+kf_+4); \
      f32x4 q0=*(const f32x4*)(GBg32+1024+kf_), q1=*(const f32x4*)(GBg32+1024+kf_+4); \
      a0[0]=(_Float16)((xa0[0]*rsA+nmA)*g0[0]+q0[0]); a0[1]=(_Float16)((xa0[1]*rsA+nmA)*g0[1]+q0[1]); \
      a0[2]=(_Float16)((xa0[2]*rsA+nmA)*g0[2]+q0[2]); a0[3]=(_Float16)((xa0[3]*rsA+nmA)*g0[3]+q0[3]); \
      a0[4]=(_Float16)((xa1[0]*rsA+nmA)*g1[0]+q1[0]); a0[5]=(_Float16)((xa1[1]*rsA+nmA)*g1[1]+q1[1]); \
      a0[6]=(_Float16)((xa1[2]*rsA+nmA)*g1[2]+q1[2]); a0[7]=(_Float16)((xa1[3]*rsA+nmA)*g1[3]+q1[3]); \
      a1[0]=(_Float16)((xb0[0]*rsB+nmB)*g0[0]+q0[0]); a1[1]=(_Float16)((xb0[1]*rsB+nmB)*g0[1]+q0[1]); \
      a1[2]=(_Float16)((xb0[2]*rsB+nmB)*g0[2]+q0[2]); a1[3]=(_Float16)((xb0[3]*rsB+nmB)*g0[3]+q0[3]); \
      a1[4]=(_Float16)((xb1[0]*rsB+nmB)*g1[0]+q1[0]); a1[5]=(_Float16)((xb1[1]*rsB+nmB)*g1[1]+q1[1]); \
      a1[6]=(_Float16)((xb1[2]*rsB+nmB)*g1[2]+q1[2]); a1[7]=(_Float16)((xb1[3]*rsB+nmB)*g1[3]+q1[3]); \
    } else { \
      a0=__builtin_bit_cast(f16x8,PX(s_,0,0)); a1=__builtin_bit_cast(f16x8,PX(s_,1,0)); \
    } \
    const int kb_=kf_*2; \
    f16x8 bF=*(const f16x8*)(WF + (kb_^swl)); \
    f16x8 bC=*(const f16x8*)(WC + (kb_^swl)); \
    accF0=__builtin_amdgcn_mfma_f32_16x16x32_f16(a0,bF,accF0,0,0,0); \
    accF1=__builtin_amdgcn_mfma_f32_16x16x32_f16(a1,bF,accF1,0,0,0); \
    accC0=__builtin_amdgcn_mfma_f32_16x16x32_f16(a0,bC,accC0,0,0,0); \
    accC1=__builtin_amdgcn_mfma_f32_16x16x32_f16(a1,bC,accC1,0,0,0); \
  }while(0)

#define CHX(c,NW) do{ if ((c)<12) LOADC_X((c)+4); WAITV(NW); PROC_X(c); }while(0)

// ---------------- pre-pass 1: fp32 (D,D) row-major -> fp16 transposed fused layout ----------------
extern "C" __global__ void __launch_bounds__(256,1) crs_prepass(
    const float* __restrict__ Wf, const float* __restrict__ Uf,
    const float* __restrict__ Wc, const float* __restrict__ Uc,
    unsigned short* __restrict__ WT)
{
  int bid = blockIdx.x;
  int kt  = bid & 15;
  int ct  = (bid>>4) & 31;
  int sel = (bid>>9) & 3;
  int i   = bid >> 11;
  int tid = threadIdx.x;
  int kq  = tid >> 5;
  int cc  = tid & 31;
  const float* sp;
  if      (sel==0) sp = Wf;
  else if (sel==1) sp = Uf;
  else if (sel==2) sp = Wc;
  else             sp = Uc;
  sp += (size_t)i * 1048576;
  int cl = ct*32 + cc;
  int k0 = kt*64 + kq*8;
  float f[8];
  #pragma unroll
  for (int e=0;e<8;++e){ f[e] = sp[(size_t)(k0+e)*1024 + cl]; }
  int cg = ((sel>>1) ? 1024 : 0) + cl;
  int ks = sel & 1;
  size_t idx = ((size_t)(i*2048 + cg)*2 + ks)*1024 + k0;
  uint4 pk;
  pk.x = pk2h(f[0], f[1]);
  pk.y = pk2h(f[2], f[3]);
  pk.z = pk2h(f[4], f[5]);
  pk.w = pk2h(f[6], f[7]);
  *(uint4*)(WT + idx) = pk;
}

// ---------------- pre-pass 2: x row-stats + initial state -> fp16 ----------------
extern "C" __global__ void __launch_bounds__(256,1) crs_prep2(
    const float* __restrict__ x, const float* __restrict__ st0,
    float* __restrict__ xstat, unsigned short* __restrict__ st16)
{
  __shared__ float2 part[256];
  int bid=blockIdx.x, tid=threadIdx.x;
  int rr=tid>>3, ss=tid&7;
  if (bid<T_){
    const float4* p4=(const float4*)(x+(size_t)bid*BD_+rr*1024+ss*128);
    float s1=0.f,s2=0.f;
    #pragma unroll 8
    for (int q=0;q<32;++q){ float4 a=p4[q]; s1+=a.x+a.y+a.z+a.w; s2+=a.x*a.x+a.y*a.y+a.z*a.z+a.w*a.w; }
    part[tid]=make_float2(s1,s2);
    __syncthreads();
    if (tid<32){
      float a1=0.f,a2=0.f;
      #pragma unroll
      for (int e=0;e<8;++e){ float2 pp=part[tid*8+e]; a1+=pp.x; a2+=pp.y; }
      xstat[bid*64+tid*2]=a1; xstat[bid*64+tid*2+1]=a2;
    }
  } else {
    int i2=bid-T_;
    const float4* p4=(const float4*)(st0+(size_t)i2*BD_+rr*1024+ss*128);
    uint4* dst=(uint4*)(st16+((size_t)i2*2)*32768+rr*1024+ss*128);
    #pragma unroll
    for (int q=0;q<16;++q){
      float4 a=p4[2*q], b=p4[2*q+1];
      uint4 pk; pk.x=pk2h(a.x,a.y); pk.y=pk2h(a.z,a.w); pk.z=pk2h(b.x,b.y); pk.w=pk2h(b.z,b.w);
      dst[q]=pk;
    }
  }
}

// ---------------- main persistent kernel ----------------
extern "C" __global__ void __launch_bounds__(TPB,1) crs_main(
    const float* __restrict__ x, const float* __restrict__ st0,
    const float* __restrict__ bfv, const float* __restrict__ bcv,
    const float* __restrict__ pg, const float* __restrict__ pb,
    const float* __restrict__ sg, const float* __restrict__ sbv,
    float* __restrict__ y, float* __restrict__ ostate,
    const unsigned short* __restrict__ WT, char* __restrict__ ws)
{
  extern __shared__ char smem[];
  const int tid=threadIdx.x, w=blockIdx.x;
  const int li=w>>6, wr=w&63;
  const int lane=tid&63, v=tid>>6;        // v = k-quarter
  const int l15=lane&15, lg=(lane>>4)&3;
  const int kq = v*32 + lg*8;             // fused-k element offset within a 128-chunk
  const int col=lane&15, rp=lane>>4;      // epilogue mapping
  const int r0=v*8+rp, r1=v*8+4+rp;
  const int sseg=tid&7;

  unsigned* root=(unsigned*)(ws+WSO_ROOT);
  unsigned* grpc=(unsigned*)(ws+WSO_GRP)+(w>>5)*64;
  float* hstat=(float*)(ws+WSO_HSTAT);
  float* ystat=(float*)(ws+WSO_YSTAT);
  float* xstat=(float*)(ws+WSO_XSTAT);
  unsigned short* st16=(unsigned short*)(ws+WSO_ST16);
  unsigned short* h16=(unsigned short*)(ws+WSO_H16);
  float* NSf=(float*)(smem+LDS_NS);
  float* BIAS=(float*)(smem+LDS_BIAS);
  float* SGSB=(float*)(smem+LDS_SGSB);

  // ---- one-time init: weights -> LDS (swizzled)
  {
    int lc=tid>>3;
    int cgl=(lc>>4)*1024 + wr*16 + (lc&15);
    const unsigned short* src=WT + ((size_t)li*2048+cgl)*2048;
    char* dcol = smem + LDS_W + lc*4096;
    int sw2=(lc&7)<<4;
    #pragma unroll
    for (int n=0;n<32;++n){
      int q=sseg+n*8;
      uint4 d=*(const uint4*)(src+q*8);
      *(uint4*)(dcol + ((q*16)^sw2)) = d;
    }
  }
  if (li==0){
    float* g32=(float*)(smem+LDS_GB);
    for (int k=tid;k<1024;k+=TPB){ g32[k]=pg[k]; g32[1024+k]=pb[k]; }
  } else {
    unsigned* g16=(unsigned*)(smem+LDS_GB);
    for (int k=tid;k<512;k+=TPB){
      g16[k]    =pk2h(pg[li*1024+2*k], pg[li*1024+2*k+1]);
      g16[512+k]=pk2h(pb[li*1024+2*k], pb[li*1024+2*k+1]);
    }
  }
  if (tid<16) BIAS[tid]=bfv[li*1024+wr*16+tid];
  else if (tid<32) BIAS[tid]=bcv[li*1024+wr*16+(tid-16)];
  if (li==3){
    if (tid<16) SGSB[tid]=sg[wr*16+tid];
    else if (tid<32) SGSB[tid]=sbv[wr*16+(tid-16)];
  }
  f32x2 sreg, pns={0.f,0.f};
  sreg.x = st0[(size_t)li*BD_ + (size_t)r0*D_ + wr*16+col];
  sreg.y = st0[(size_t)li*BD_ + (size_t)r1*D_ + wr*16+col];
  __syncthreads();

  for (int p=0;p<T_+L_-1;++p){
    int t=p-li;
    if (t>=0 && t<T_){
      // ---- front-matter (r6 structure)
      if (li==3 && t>=1){
        const float* stY=ystat+((t-1)&3)*64;
        float gv=SGSB[col], bv=SGSB[16+col];
        float s1=cload1(stY+r0*2), s2=cload1(stY+r0*2+1);
        float m0=s1*(1.f/1024.f);
        float rs0=rsqrtf(s2*(1.f/1024.f)-m0*m0+EPSF);
        y[(size_t)(t-1)*BD_+(size_t)r0*D_+wr*16+col]=(pns.x-m0)*rs0*gv+bv;
        float s3=cload1(stY+r1*2), s4=cload1(stY+r1*2+1);
        float m1=s3*(1.f/1024.f);
        float rs1=rsqrtf(s4*(1.f/1024.f)-m1*m1+EPSF);
        y[(size_t)(t-1)*BD_+(size_t)r1*D_+wr*16+col]=(pns.y-m1)*rs1*gv+bv;
      }
      if (v==0){
        if (wr==0 && t>=2){
          float* zp=(li<3)? (hstat+(li*4+((t-2)&3))*64) : (ystat+((t-2)&3)*64);
          cstore1(zp+tid,0.f);
        }
        if (tid<32){
          float s1,s2;
          if (li==0){ s1=xstat[t*64+tid*2]; s2=xstat[t*64+tid*2+1]; }
          else { const float* hs=hstat+((li-1)*4+(t&3))*64; s1=cload1(hs+tid*2); s2=cload1(hs+tid*2+1); }
          float m=s1*(1.f/1024.f);
          ((float2*)(smem+LDS_MRS))[tid]=make_float2(m, rsqrtf(s2*(1.f/1024.f)-m*m+EPSF));
        }
      }
      asm volatile("s_waitcnt vmcnt(0)" ::: "memory");

      const unsigned short* h16b = (li>0)? (h16 + ((size_t)(li-1)*2+(size_t)(t&1))*32768) : (const unsigned short*)0;
      u64 sbH = (li==0)? (u64)(uintptr_t)(x + (size_t)t*BD_) : (u64)(uintptr_t)h16b;
      u64 sbS = (u64)(uintptr_t)(st16 + ((size_t)li*2+(size_t)(t&1))*32768);
      const int voA = l15*2048 + kq*2, voB = voA + 32768;
      const int vxA = l15*4096 + kq*4, vxB = vxA + 65536;

      f32x4 accF0={0,0,0,0}, accF1={0,0,0,0}, accC0={0,0,0,0}, accC1={0,0,0,0};
      if (li==0){
        u32x4 pay[20];
        LOADC_X(0); LOADC_X(1); LOADC_X(2); LOADC_X(3);
        BARS;
        float2 mrA=((const float2*)(smem+LDS_MRS))[l15];
        float2 mrB=((const float2*)(smem+LDS_MRS))[16+l15];
        const char* WF = smem + LDS_W + l15*4096;
        const char* WC = smem + LDS_W + (16+l15)*4096;
        const int swl = (l15&7)<<4;
        const float rsA = mrA.y, rsB = mrB.y;
        const float nmA = -mrA.x*rsA, nmB = -mrB.x*rsB;
        const float* GBg32 = (const float*)(smem+LDS_GB);
        CHX(0,16);CHX(1,16);CHX(2,16);CHX(3,16);CHX(4,14);CHX(5,12);CHX(6,10);CHX(7,8);
        CHX(8,8);CHX(9,8);CHX(10,8);CHX(11,8);CHX(12,6);CHX(13,4);CHX(14,2);CHX(15,0);
      } else {
        u32x4 pay[12];
        LOADC_N(0); LOADC_N(1); LOADC_N(2); LOADC_N(3); LOADC_N(4);
        BARS;
        float2 mrA=((const float2*)(smem+LDS_MRS))[l15];
        float2 mrB=((const float2*)(smem+LDS_MRS))[16+l15];
        const char* WF = smem + LDS_W + l15*4096;
        const char* WC = smem + LDS_W + (16+l15)*4096;
        const int swl = (l15&7)<<4;
        const _Float16 hrA=(_Float16)mrA.y, hmA=(_Float16)(-mrA.x*mrA.y);
        const _Float16 hrB=(_Float16)mrB.y, hmB=(_Float16)(-mrB.x*mrB.y);
        const f16x8 rsA8={hrA,hrA,hrA,hrA,hrA,hrA,hrA,hrA};
        const f16x8 nmA8={hmA,hmA,hmA,hmA,hmA,hmA,hmA,hmA};
        const f16x8 rsB8={hrB,hrB,hrB,hrB,hrB,hrB,hrB,hrB};
        const f16x8 nmB8={hmB,hmB,hmB,hmB,hmB,hmB,hmB,hmB};
        const unsigned* GBg16 = (const unsigned*)(smem+LDS_GB);
        CHN(0,10);CHN(1,10);CHN(2,10);CHN(3,10);CHN(4,10);CHN(5,10);
        CHN(6,10);CHN(7,10);CHN(8,10);CHN(9,10);CHN(10,10);
        CHN(11,8);CHN(12,6);CHN(13,4);CHN(14,2);CHN(15,0);
      }

      *(f32x4*)(smem+LDS_DUMP + (((v*4+0)*64+lane)<<4)) = accF0;
      *(f32x4*)(smem+LDS_DUMP + (((v*4+1)*64+lane)<<4)) = accF1;
      *(f32x4*)(smem+LDS_DUMP + (((v*4+2)*64+lane)<<4)) = accC0;
      *(f32x4*)(smem+LDS_DUMP + (((v*4+3)*64+lane)<<4)) = accC1;
      BARS;

      {
        const int rtl = v>>1;
        const int lg20 = (v&1)*2, lg21 = (v&1)*2+1;
        float fF0=0.f,fF1=0.f,fC0=0.f,fC1=0.f;
        #pragma unroll
        for (int v2=0;v2<4;++v2){
          const char* db = smem+LDS_DUMP + v2*4096;
          fF0 += *(const float*)(db + (((0+rtl)*64 + lg20*16+col)<<4) + rp*4);
          fF1 += *(const float*)(db + (((0+rtl)*64 + lg21*16+col)<<4) + rp*4);
          fC0 += *(const float*)(db + (((2+rtl)*64 + lg20*16+col)<<4) + rp*4);
          fC1 += *(const float*)(db + (((2+rtl)*64 + lg21*16+col)<<4) + rp*4);
        }
        float bfc=BIAS[col], bcc=BIAS[16+col];
        float preF0=fminf(fmaxf(fF0+bfc,-30.f),30.f);
        float preC0=fminf(fmaxf(fC0+bcc,-30.f),30.f);
        float preF1=fminf(fmaxf(fF1+bfc,-30.f),30.f);
        float preC1=fminf(fmaxf(fC1+bcc,-30.f),30.f);
        float fg0=1.f/(1.f+__expf(-preF0)), e0=__expf(-2.f*preC0);
        float cd0=(1.f-e0)/(1.f+e0);
        float fg1=1.f/(1.f+__expf(-preF1)), e1=__expf(-2.f*preC1);
        float cd1=(1.f-e1)/(1.f+e1);
        float ns0=fg0*sreg.x+(1.f-fg0)*cd0;
        float ns1=fg1*sreg.y+(1.f-fg1)*cd1;
        sreg.x=ns0; sreg.y=ns1;
        if (li==3){ pns.x=ns0; pns.y=ns1; }
        float a1=ns0, a2=ns0*ns0, a3=ns1, a4=ns1*ns1;
        #pragma unroll
        for (int m=1;m<16;m<<=1){
          a1+=__shfl_xor(a1,m); a2+=__shfl_xor(a2,m);
          a3+=__shfl_xor(a3,m); a4+=__shfl_xor(a4,m);
        }
        float* stadd=(li<3)? (hstat+(li*4+(t&3))*64) : (ystat+(t&3)*64);
        if (col==0){
          atomicAdd(stadd+r0*2,   a1); atomicAdd(stadd+r0*2+1, a2);
          atomicAdd(stadd+r1*2,   a3); atomicAdd(stadd+r1*2+1, a4);
        }
        NSf[r0*NSTR+col]=ns0;
        NSf[r1*NSTR+col]=ns1;
      }
      BARS;

      if (lane<16){
        int row = v*8 + (lane>>1), hf = lane&1;
        const float* nr = NSf + row*NSTR + hf*8;
        f32x4 q0 = *(const f32x4*)nr, q1 = *(const f32x4*)(nr+4);
        unsigned w0=pk2h(q0[0],q0[1]), w1=pk2h(q0[2],q0[3]);
        unsigned w2=pk2h(q1[0],q1[1]), w3=pk2h(q1[2],q1[3]);
        unsigned short* sd = st16 + ((size_t)li*2+(size_t)((t+1)&1))*32768 + row*1024 + wr*16 + hf*8;
        cstore16(sd, w0, w1, w2, w3);
        if (li<3){
          unsigned short* hd = h16 + ((size_t)li*2+(size_t)(t&1))*32768 + row*1024 + wr*16 + hf*8;
          cstore16(hd, w0, w1, w2, w3);
        }
        if (t==T_-1){
          float* op = ostate + (size_t)li*BD_ + (size_t)row*D_ + wr*16 + hf*8;
          *(f32x4*)op = q0; *(f32x4*)(op+4) = q1;
        }
      }
    }
    // ---- hierarchical fence-free grid barrier (no L2 invalidate — r8 lesson)
    asm volatile("s_waitcnt vmcnt(0)" ::: "memory");
    __syncthreads();
    if (tid==0){
      unsigned old=__hip_atomic_fetch_add(grpc,1u,__ATOMIC_RELAXED,__HIP_MEMORY_SCOPE_AGENT);
      if (old==(unsigned)(p*32+31))
        __hip_atomic_fetch_add(root,1u,__ATOMIC_RELAXED,__HIP_MEMORY_SCOPE_AGENT);
      unsigned tgt=(unsigned)((p+1)*8);
      while (__hip_atomic_load(root,__ATOMIC_RELAXED,__HIP_MEMORY_SCOPE_AGENT)<tgt)
        __builtin_amdgcn_s_sleep(2);
    }
    __syncthreads();
  }

  if (li==3){
    const float* stY=ystat+((T_-1)&3)*64;
    float gv=SGSB[col], bv=SGSB[16+col];
    float s1=cload1(stY+r0*2), s2=cload1(stY+r0*2+1);
    float m0=s1*(1.f/1024.f);
    float rs0=rsqrtf(s2*(1.f/1024.f)-m0*m0+EPSF);
    y[(size_t)(T_-1)*BD_+(size_t)r0*D_+wr*16+col]=(pns.x-m0)*rs0*gv+bv;
    float s3=cload1(stY+r1*2), s4=cload1(stY+r1*2+1);
    float m1=s3*(1.f/1024.f);
    float rs1=rsqrtf(s4*(1.f/1024.f)-m1*m1+EPSF);
    y[(size_t)(T_-1)*BD_+(size_t)r1*D_+wr*16+col]=(pns.y-m1)*rs1*gv+bv;
  }
}

extern "C" void kernel_launch(void* const* d_in, const int* in_sizes, int n_in,
                              void* d_out, int out_size, void* d_ws, size_t ws_size,
                              hipStream_t stream){
  (void)in_sizes; (void)n_in; (void)out_size; (void)ws_size;
  const float* x   = (const float*)d_in[0];
  const float* st0 = (const float*)d_in[1];
  const float* Wf  = (const float*)d_in[2];
  const float* Uf  = (const float*)d_in[3];
  const float* bfv = (const float*)d_in[4];
  const float* Wc  = (const float*)d_in[5];
  const float* Uc  = (const float*)d_in[6];
  const float* bcv = (const float*)d_in[7];
  const float* pg  = (const float*)d_in[8];
  const float* pb  = (const float*)d_in[9];
  const float* sg  = (const float*)d_in[10];
  const float* sbv = (const float*)d_in[11];

  float* y      = (float*)d_out;
  float* ostate = y + (size_t)T_*BD_;
  char* ws = (char*)d_ws;

  (void)hipMemsetAsync(ws, 0, 8192, stream);
  hipLaunchKernelGGL(crs_prepass, dim3(8192), dim3(256), 0, stream,
                     Wf, Uf, Wc, Uc, (unsigned short*)(ws+WSO_WT));
  hipLaunchKernelGGL(crs_prep2, dim3(T_+L_), dim3(256), 0, stream,
                     x, st0, (float*)(ws+WSO_XSTAT), (unsigned short*)(ws+WSO_ST16));
  (void)hipFuncSetAttribute((const void*)crs_main, hipFuncAttributeMaxDynamicSharedMemorySize, LDS_TOTAL);
  hipLaunchKernelGGL(crs_main, dim3(NWG), dim3(TPB), LDS_TOTAL, stream,
                     x, st0, bfv, bcv, pg, pb, sg, sbv, y, ostate,
                     (const unsigned short*)(ws+WSO_WT), ws);
}

// Round 11
// 8188.010 us; speedup vs baseline: 1.4891x; 1.0738x over previous
//
#include <hip/hip_runtime.h>
#include <cstdint>
#include <cstddef>

#define T_ 512
#define B_ 32
#define D_ 1024
#define L_ 4
#define BD_ (B_*D_)
#define TPB 256
#define NWG 256
#define EPSF 1e-5f

typedef _Float16 f16x8 __attribute__((ext_vector_type(8)));
typedef float f32x4 __attribute__((ext_vector_type(4)));
typedef float f32x2 __attribute__((ext_vector_type(2)));
typedef unsigned int u32x4 __attribute__((ext_vector_type(4)));
typedef unsigned long long u64;

// workspace layout (bytes)
#define WSO_PROG   0         // 4 layer progress counters, 256B apart
#define WSO_HSTAT  4096
#define WSO_YSTAT  7168
#define WSO_XSTAT  8192
#define WSO_ST16   139264
#define WSO_H16    663552
#define WSO_WT     2097152

// LDS layout (bytes)
#define LDS_W     0        // 32 cols x 2048 fused-k fp16, col stride 4096, XOR-swizzled
#define LDS_DUMP  131072   // 16 tiles x 64 lanes x 16B = 16384
#define LDS_GB    147456   // li0: f32 g[1024]|b[1024] (8KB); li>0: u32 gpk[512]|bpk[512] (4KB)
#define LDS_MRS   155648   // 32 float2
#define LDS_NS    155904   // 32 rows x 80B (20 floats)
#define LDS_BIAS  158464   // 32 f32 (bf|bc)
#define LDS_SGSB  158592   // 32 f32 (sg|sb)
#define LDS_TOTAL 158720
#define NSTR 20

__device__ __forceinline__ unsigned pk2h(float a, float b){
  _Float16 ha=(_Float16)a, hb=(_Float16)b;
  return (unsigned)__builtin_bit_cast(unsigned short,ha) |
         ((unsigned)__builtin_bit_cast(unsigned short,hb)<<16);
}
__device__ __forceinline__ float cload1(const float* p){
  unsigned v=__hip_atomic_load((const unsigned*)(const void*)p,__ATOMIC_RELAXED,__HIP_MEMORY_SCOPE_AGENT);
  return __builtin_bit_cast(float,v);
}
__device__ __forceinline__ void cstore1(float* p, float v){
  __hip_atomic_store((unsigned*)(void*)p,__builtin_bit_cast(unsigned,v),__ATOMIC_RELAXED,__HIP_MEMORY_SCOPE_AGENT);
}
__device__ __forceinline__ unsigned cldu(const unsigned* p){
  return __hip_atomic_load(p,__ATOMIC_RELAXED,__HIP_MEMORY_SCOPE_AGENT);
}
// 16B coherent store as 2 x u64 relaxed agent-scope atomic stores (write-through to L3)
__device__ __forceinline__ void cstore16(unsigned short* p, unsigned w0, unsigned w1, unsigned w2, unsigned w3){
  u64 lo=((u64)w1<<32)|w0, hi=((u64)w3<<32)|w2;
  __hip_atomic_store((u64*)(void*)p,     lo, __ATOMIC_RELAXED, __HIP_MEMORY_SCOPE_AGENT);
  __hip_atomic_store((u64*)(void*)(p+4), hi, __ATOMIC_RELAXED, __HIP_MEMORY_SCOPE_AGENT);
}

#define GLD(d,vo,sb)  asm volatile("global_load_dwordx4 %0, %1, %2 sc0 sc1" : "=v"(d) : "v"(vo), "s"(sb) : "memory")
#define GLDX(d,vo,sb) asm volatile("global_load_dwordx4 %0, %1, %2"          : "=v"(d) : "v"(vo), "s"(sb) : "memory")
#define WAITV(N) do{ asm volatile("s_waitcnt vmcnt(" #N ")" ::: "memory"); __builtin_amdgcn_sched_barrier(0); }while(0)
#define BARS do{ asm volatile("s_waitcnt lgkmcnt(0)" ::: "memory"); __builtin_amdgcn_s_barrier(); }while(0)

// per-chunk A loads: chunks 0-7 = h (LN applied at use), 8-15 = state (raw). Depth-3, 4 slots (r6 optimum).
#define LOADC(c) do{ const int s_=(c)&3; \
  if (ISX){ \
    if ((c)<8){ \
      GLDX(pay[s_][0][0], vxA+(c)*512,    sbH); GLDX(pay[s_][0][1], vxA+(c)*512+16, sbH); \
      GLDX(pay[s_][1][0], vxB+(c)*512,    sbH); GLDX(pay[s_][1][1], vxB+(c)*512+16, sbH); \
    } else { \
      GLD(pay[s_][0][0], voA+((c)-8)*256, sbS); GLD(pay[s_][1][0], voB+((c)-8)*256, sbS); \
    } \
  } else { \
    if ((c)<8){ GLD(pay[s_][0][0], voA+(c)*256, sbH); GLD(pay[s_][1][0], voB+(c)*256, sbH); } \
    else      { GLD(pay[s_][0][0], voA+((c)-8)*256, sbS); GLD(pay[s_][1][0], voB+((c)-8)*256, sbS); } \
  } \
}while(0)

#define PROC(c) do{ const int s_=(c)&3; f16x8 a0,a1; \
    const int kf_=(c)*128+kq; \
    if ((c)<8){ \
      if (ISX){ \
        f32x4 xa0=__builtin_bit_cast(f32x4,pay[s_][0][0]), xa1=__builtin_bit_cast(f32x4,pay[s_][0][1]); \
        f32x4 xb0=__builtin_bit_cast(f32x4,pay[s_][1][0]), xb1=__builtin_bit_cast(f32x4,pay[s_][1][1]); \
        f32x4 g0=*(const f32x4*)(GBg32+kf_), g1=*(const f32x4*)(GBg32+kf_+4); \
        f32x4 q0=*(const f32x4*)(GBg32+1024+kf_), q1=*(const f32x4*)(GBg32+1024+kf_+4); \
        a0[0]=(_Float16)((xa0[0]*rsA+nmA)*g0[0]+q0[0]); a0[1]=(_Float16)((xa0[1]*rsA+nmA)*g0[1]+q0[1]); \
        a0[2]=(_Float16)((xa0[2]*rsA+nmA)*g0[2]+q0[2]); a0[3]=(_Float16)((xa0[3]*rsA+nmA)*g0[3]+q0[3]); \
        a0[4]=(_Float16)((xa1[0]*rsA+nmA)*g1[0]+q1[0]); a0[5]=(_Float16)((xa1[1]*rsA+nmA)*g1[1]+q1[1]); \
        a0[6]=(_Float16)((xa1[2]*rsA+nmA)*g1[2]+q1[2]); a0[7]=(_Float16)((xa1[3]*rsA+nmA)*g1[3]+q1[3]); \
        a1[0]=(_Float16)((xb0[0]*rsB+nmB)*g0[0]+q0[0]); a1[1]=(_Float16)((xb0[1]*rsB+nmB)*g0[1]+q0[1]); \
        a1[2]=(_Float16)((xb0[2]*rsB+nmB)*g0[2]+q0[2]); a1[3]=(_Float16)((xb0[3]*rsB+nmB)*g0[3]+q0[3]); \
        a1[4]=(_Float16)((xb1[0]*rsB+nmB)*g1[0]+q1[0]); a1[5]=(_Float16)((xb1[1]*rsB+nmB)*g1[1]+q1[1]); \
        a1[6]=(_Float16)((xb1[2]*rsB+nmB)*g1[2]+q1[2]); a1[7]=(_Float16)((xb1[3]*rsB+nmB)*g1[3]+q1[3]); \
      } else { \
        f16x8 g8=*(const f16x8*)(GBg16+(kf_>>1)); \
        f16x8 b8=*(const f16x8*)(GBg16+512+(kf_>>1)); \
        a0=__builtin_bit_cast(f16x8,pay[s_][0][0]); a1=__builtin_bit_cast(f16x8,pay[s_][1][0]); \
        a0=a0*rsA8+nmA8; a0=a0*g8+b8; \
        a1=a1*rsB8+nmB8; a1=a1*g8+b8; \
      } \
    } else { \
      a0=__builtin_bit_cast(f16x8,pay[s_][0][0]); a1=__builtin_bit_cast(f16x8,pay[s_][1][0]); \
    } \
    const int kb_=kf_*2; \
    f16x8 bF=*(const f16x8*)(WF + (kb_^swl)); \
    f16x8 bC=*(const f16x8*)(WC + (kb_^swl)); \
    accF0=__builtin_amdgcn_mfma_f32_16x16x32_f16(a0,bF,accF0,0,0,0); \
    accF1=__builtin_amdgcn_mfma_f32_16x16x32_f16(a1,bF,accF1,0,0,0); \
    accC0=__builtin_amdgcn_mfma_f32_16x16x32_f16(a0,bC,accC0,0,0,0); \
    accC1=__builtin_amdgcn_mfma_f32_16x16x32_f16(a1,bC,accC1,0,0,0); \
  }while(0)

#define CH(c,NW) do{ if ((c)<13) LOADC((c)+3); WAITV(NW); PROC(c); }while(0)

template<int ISX>
__device__ __forceinline__ void stage_pre(u32x4 (&pay)[4][2][2],
    u64 sbH, u64 sbS, int voA, int voB, int vxA, int vxB)
{
  LOADC(0); LOADC(1); LOADC(2);
}

template<int ISX>
__device__ __forceinline__ void chunk_run(char* smem, u32x4 (&pay)[4][2][2],
    u64 sbH, u64 sbS, int voA, int voB, int vxA, int vxB,
    int l15, int kq, float2 mrA, float2 mrB,
    f32x4& accF0, f32x4& accF1, f32x4& accC0, f32x4& accC1)
{
  const char* WF = smem + LDS_W + l15*4096;
  const char* WC = smem + LDS_W + (16+l15)*4096;
  const int swl = (l15&7)<<4;
  const float rsA = mrA.y, rsB = mrB.y;
  const float nmA = -mrA.x*rsA, nmB = -mrB.x*rsB;
  const _Float16 hrA=(_Float16)rsA, hmA=(_Float16)nmA, hrB=(_Float16)rsB, hmB=(_Float16)nmB;
  const f16x8 rsA8={hrA,hrA,hrA,hrA,hrA,hrA,hrA,hrA};
  const f16x8 nmA8={hmA,hmA,hmA,hmA,hmA,hmA,hmA,hmA};
  const f16x8 rsB8={hrB,hrB,hrB,hrB,hrB,hrB,hrB,hrB};
  const f16x8 nmB8={hmB,hmB,hmB,hmB,hmB,hmB,hmB,hmB};
  const unsigned* GBg16 = (const unsigned*)(smem+LDS_GB);
  const float* GBg32 = (const float*)(smem+LDS_GB);

  if (ISX){
    CH(0,12);CH(1,12);CH(2,12);CH(3,12);CH(4,12);CH(5,10);CH(6,8);CH(7,6);
    CH(8,6);CH(9,6);CH(10,6);CH(11,6);CH(12,6);CH(13,4);CH(14,2);CH(15,0);
  } else {
    CH(0,6);CH(1,6);CH(2,6);CH(3,6);CH(4,6);CH(5,6);CH(6,6);CH(7,6);
    CH(8,6);CH(9,6);CH(10,6);CH(11,6);CH(12,6);CH(13,4);CH(14,2);CH(15,0);
  }
}

// ---------------- pre-pass 1: fp32 (D,D) row-major -> fp16 transposed fused layout ----------------
extern "C" __global__ void __launch_bounds__(256,1) crs_prepass(
    const float* __restrict__ Wf, const float* __restrict__ Uf,
    const float* __restrict__ Wc, const float* __restrict__ Uc,
    unsigned short* __restrict__ WT)
{
  int bid = blockIdx.x;
  int kt  = bid & 15;
  int ct  = (bid>>4) & 31;
  int sel = (bid>>9) & 3;
  int i   = bid >> 11;
  int tid = threadIdx.x;
  int kq  = tid >> 5;
  int cc  = tid & 31;
  const float* sp;
  if      (sel==0) sp = Wf;
  else if (sel==1) sp = Uf;
  else if (sel==2) sp = Wc;
  else             sp = Uc;
  sp += (size_t)i * 1048576;
  int cl = ct*32 + cc;
  int k0 = kt*64 + kq*8;
  float f[8];
  #pragma unroll
  for (int e=0;e<8;++e){ f[e] = sp[(size_t)(k0+e)*1024 + cl]; }
  int cg = ((sel>>1) ? 1024 : 0) + cl;
  int ks = sel & 1;
  size_t idx = ((size_t)(i*2048 + cg)*2 + ks)*1024 + k0;
  uint4 pk;
  pk.x = pk2h(f[0], f[1]);
  pk.y = pk2h(f[2], f[3]);
  pk.z = pk2h(f[4], f[5]);
  pk.w = pk2h(f[6], f[7]);
  *(uint4*)(WT + idx) = pk;
}

// ---------------- pre-pass 2: x row-stats + initial state -> fp16 ----------------
extern "C" __global__ void __launch_bounds__(256,1) crs_prep2(
    const float* __restrict__ x, const float* __restrict__ st0,
    float* __restrict__ xstat, unsigned short* __restrict__ st16)
{
  __shared__ float2 part[256];
  int bid=blockIdx.x, tid=threadIdx.x;
  int rr=tid>>3, ss=tid&7;
  if (bid<T_){
    const float4* p4=(const float4*)(x+(size_t)bid*BD_+rr*1024+ss*128);
    float s1=0.f,s2=0.f;
    #pragma unroll 8
    for (int q=0;q<32;++q){ float4 a=p4[q]; s1+=a.x+a.y+a.z+a.w; s2+=a.x*a.x+a.y*a.y+a.z*a.z+a.w*a.w; }
    part[tid]=make_float2(s1,s2);
    __syncthreads();
    if (tid<32){
      float a1=0.f,a2=0.f;
      #pragma unroll
      for (int e=0;e<8;++e){ float2 pp=part[tid*8+e]; a1+=pp.x; a2+=pp.y; }
      xstat[bid*64+tid*2]=a1; xstat[bid*64+tid*2+1]=a2;
    }
  } else {
    int i2=bid-T_;
    const float4* p4=(const float4*)(st0+(size_t)i2*BD_+rr*1024+ss*128);
    uint4* dst=(uint4*)(st16+((size_t)i2*2)*32768+rr*1024+ss*128);
    #pragma unroll
    for (int q=0;q<16;++q){
      float4 a=p4[2*q], b=p4[2*q+1];
      uint4 pk; pk.x=pk2h(a.x,a.y); pk.y=pk2h(a.z,a.w); pk.z=pk2h(b.x,b.y); pk.w=pk2h(b.z,b.w);
      dst[q]=pk;
    }
  }
}

// ---------------- main persistent kernel: per-layer dataflow (no global barrier) ----------------
extern "C" __global__ void __launch_bounds__(TPB,1) crs_main(
    const float* __restrict__ x, const float* __restrict__ st0,
    const float* __restrict__ bfv, const float* __restrict__ bcv,
    const float* __restrict__ pg, const float* __restrict__ pb,
    const float* __restrict__ sg, const float* __restrict__ sbv,
    float* __restrict__ y, float* __restrict__ ostate,
    const unsigned short* __restrict__ WT, char* __restrict__ ws)
{
  extern __shared__ char smem[];
  const int tid=threadIdx.x, w=blockIdx.x;
  const int li=w>>6, wr=w&63;
  const int lane=tid&63, v=tid>>6;        // v = k-quarter
  const int l15=lane&15, lg=(lane>>4)&3;
  const int kq = v*32 + lg*8;
  const int col=lane&15, rp=lane>>4;
  const int r0=v*8+rp, r1=v*8+4+rp;
  const int sseg=tid&7;

  unsigned* prog=(unsigned*)(ws+WSO_PROG);   // prog[li*64]: aggregate arrivals (64 per step)
  float* hstat=(float*)(ws+WSO_HSTAT);
  float* ystat=(float*)(ws+WSO_YSTAT);
  float* xstat=(float*)(ws+WSO_XSTAT);
  unsigned short* st16=(unsigned short*)(ws+WSO_ST16);
  unsigned short* h16=(unsigned short*)(ws+WSO_H16);
  float* NSf=(float*)(smem+LDS_NS);
  float* BIAS=(float*)(smem+LDS_BIAS);
  float* SGSB=(float*)(smem+LDS_SGSB);

  // ---- one-time init: weights -> LDS (swizzled)
  {
    int lc=tid>>3;
    int cgl=(lc>>4)*1024 + wr*16 + (lc&15);
    const unsigned short* src=WT + ((size_t)li*2048+cgl)*2048;
    char* dcol = smem + LDS_W + lc*4096;
    int sw2=(lc&7)<<4;
    #pragma unroll
    for (int n=0;n<32;++n){
      int q=sseg+n*8;
      uint4 d=*(const uint4*)(src+q*8);
      *(uint4*)(dcol + ((q*16)^sw2)) = d;
    }
  }
  if (li==0){
    float* g32=(float*)(smem+LDS_GB);
    for (int k=tid;k<1024;k+=TPB){ g32[k]=pg[k]; g32[1024+k]=pb[k]; }
  } else {
    unsigned* g16=(unsigned*)(smem+LDS_GB);
    for (int k=tid;k<512;k+=TPB){
      g16[k]    =pk2h(pg[li*1024+2*k], pg[li*1024+2*k+1]);
      g16[512+k]=pk2h(pb[li*1024+2*k], pb[li*1024+2*k+1]);
    }
  }
  if (tid<16) BIAS[tid]=bfv[li*1024+wr*16+tid];
  else if (tid<32) BIAS[tid]=bcv[li*1024+wr*16+(tid-16)];
  if (li==3){
    if (tid<16) SGSB[tid]=sg[wr*16+tid];
    else if (tid<32) SGSB[tid]=sbv[wr*16+(tid-16)];
  }
  f32x2 sreg, pns={0.f,0.f};
  sreg.x = st0[(size_t)li*BD_ + (size_t)r0*D_ + wr*16+col];
  sreg.y = st0[(size_t)li*BD_ + (size_t)r1*D_ + wr*16+col];
  __syncthreads();

  for (int t=0; t<T_; ++t){
    // ---- dataflow wait: own-layer state ready, upstream h(t) ready, downstream consumed h(t-2)
    if (tid==0){
      const unsigned ow=64u*(unsigned)t;
      const unsigned uw=64u*(unsigned)(t+1);
      const unsigned dw=(t>=2)? 64u*(unsigned)(t-1) : 0u;
      for(;;){
        bool ok = (cldu(prog+li*64) >= ow);
        if (ok && li>0) ok = (cldu(prog+(li-1)*64) >= uw);
        if (ok && li<3) ok = (cldu(prog+(li+1)*64) >= dw);
        if (ok) break;
        __builtin_amdgcn_s_sleep(1);
      }
    }
    __syncthreads();

    // ---- front-matter
    if (li==3 && t>=1){
      const float* stY=ystat+((t-1)&3)*64;
      float gv=SGSB[col], bv=SGSB[16+col];
      float s1=cload1(stY+r0*2), s2=cload1(stY+r0*2+1);
      float m0=s1*(1.f/1024.f);
      float rs0=rsqrtf(s2*(1.f/1024.f)-m0*m0+EPSF);
      y[(size_t)(t-1)*BD_+(size_t)r0*D_+wr*16+col]=(pns.x-m0)*rs0*gv+bv;
      float s3=cload1(stY+r1*2), s4=cload1(stY+r1*2+1);
      float m1=s3*(1.f/1024.f);
      float rs1=rsqrtf(s4*(1.f/1024.f)-m1*m1+EPSF);
      y[(size_t)(t-1)*BD_+(size_t)r1*D_+wr*16+col]=(pns.y-m1)*rs1*gv+bv;
    }
    if (v==0){
      if (wr==0 && t>=2){
        float* zp=(li<3)? (hstat+(li*4+((t-2)&3))*64) : (ystat+((t-2)&3)*64);
        cstore1(zp+tid,0.f);
      }
      if (tid<32){
        float s1,s2;
        if (li==0){ s1=xstat[t*64+tid*2]; s2=xstat[t*64+tid*2+1]; }
        else { const float* hs=hstat+((li-1)*4+(t&3))*64; s1=cload1(hs+tid*2); s2=cload1(hs+tid*2+1); }
        float m=s1*(1.f/1024.f);
        ((float2*)(smem+LDS_MRS))[tid]=make_float2(m, rsqrtf(s2*(1.f/1024.f)-m*m+EPSF));
      }
    }
    asm volatile("s_waitcnt vmcnt(0)" ::: "memory");

    const unsigned short* h16b = (li>0)? (h16 + ((size_t)(li-1)*2+(size_t)(t&1))*32768) : (const unsigned short*)0;
    u64 sbH = (li==0)? (u64)(uintptr_t)(x + (size_t)t*BD_) : (u64)(uintptr_t)h16b;
    u64 sbS = (u64)(uintptr_t)(st16 + ((size_t)li*2+(size_t)(t&1))*32768);
    const int voA = l15*2048 + kq*2, voB = voA + 32768;
    const int vxA = l15*4096 + kq*4, vxB = vxA + 65536;
    u32x4 pay[4][2][2];
    if (li==0) stage_pre<1>(pay, sbH, sbS, voA, voB, vxA, vxB);
    else       stage_pre<0>(pay, sbH, sbS, voA, voB, vxA, vxB);
    BARS;
    float2 mrA=((const float2*)(smem+LDS_MRS))[l15];
    float2 mrB=((const float2*)(smem+LDS_MRS))[16+l15];

    f32x4 accF0={0,0,0,0}, accF1={0,0,0,0}, accC0={0,0,0,0}, accC1={0,0,0,0};
    if (li==0) chunk_run<1>(smem, pay, sbH, sbS, voA, voB, vxA, vxB, l15, kq, mrA, mrB, accF0, accF1, accC0, accC1);
    else       chunk_run<0>(smem, pay, sbH, sbS, voA, voB, vxA, vxB, l15, kq, mrA, mrB, accF0, accF1, accC0, accC1);

    *(f32x4*)(smem+LDS_DUMP + (((v*4+0)*64+lane)<<4)) = accF0;
    *(f32x4*)(smem+LDS_DUMP + (((v*4+1)*64+lane)<<4)) = accF1;
    *(f32x4*)(smem+LDS_DUMP + (((v*4+2)*64+lane)<<4)) = accC0;
    *(f32x4*)(smem+LDS_DUMP + (((v*4+3)*64+lane)<<4)) = accC1;
    BARS;

    {
      const int rtl = v>>1;
      const int lg20 = (v&1)*2, lg21 = (v&1)*2+1;
      float fF0=0.f,fF1=0.f,fC0=0.f,fC1=0.f;
      #pragma unroll
      for (int v2=0;v2<4;++v2){
        const char* db = smem+LDS_DUMP + v2*4096;
        fF0 += *(const float*)(db + (((0+rtl)*64 + lg20*16+col)<<4) + rp*4);
        fF1 += *(const float*)(db + (((0+rtl)*64 + lg21*16+col)<<4) + rp*4);
        fC0 += *(const float*)(db + (((2+rtl)*64 + lg20*16+col)<<4) + rp*4);
        fC1 += *(const float*)(db + (((2+rtl)*64 + lg21*16+col)<<4) + rp*4);
      }
      float bfc=BIAS[col], bcc=BIAS[16+col];
      float preF0=fminf(fmaxf(fF0+bfc,-30.f),30.f);
      float preC0=fminf(fmaxf(fC0+bcc,-30.f),30.f);
      float preF1=fminf(fmaxf(fF1+bfc,-30.f),30.f);
      float preC1=fminf(fmaxf(fC1+bcc,-30.f),30.f);
      float fg0=1.f/(1.f+__expf(-preF0)), e0=__expf(-2.f*preC0);
      float cd0=(1.f-e0)/(1.f+e0);
      float fg1=1.f/(1.f+__expf(-preF1)), e1=__expf(-2.f*preC1);
      float cd1=(1.f-e1)/(1.f+e1);
      float ns0=fg0*sreg.x+(1.f-fg0)*cd0;
      float ns1=fg1*sreg.y+(1.f-fg1)*cd1;
      sreg.x=ns0; sreg.y=ns1;
      if (li==3){ pns.x=ns0; pns.y=ns1; }
      float a1=ns0, a2=ns0*ns0, a3=ns1, a4=ns1*ns1;
      #pragma unroll
      for (int m=1;m<16;m<<=1){
        a1+=__shfl_xor(a1,m); a2+=__shfl_xor(a2,m);
        a3+=__shfl_xor(a3,m); a4+=__shfl_xor(a4,m);
      }
      float* stadd=(li<3)? (hstat+(li*4+(t&3))*64) : (ystat+(t&3)*64);
      if (col==0){
        atomicAdd(stadd+r0*2,   a1); atomicAdd(stadd+r0*2+1, a2);
        atomicAdd(stadd+r1*2,   a3); atomicAdd(stadd+r1*2+1, a4);
      }
      NSf[r0*NSTR+col]=ns0;
      NSf[r1*NSTR+col]=ns1;
    }
    BARS;

    if (lane<16){
      int row = v*8 + (lane>>1), hf = lane&1;
      const float* nr = NSf + row*NSTR + hf*8;
      f32x4 q0 = *(const f32x4*)nr, q1 = *(const f32x4*)(nr+4);
      unsigned w0=pk2h(q0[0],q0[1]), w1=pk2h(q0[2],q0[3]);
      unsigned w2=pk2h(q1[0],q1[1]), w3=pk2h(q1[2],q1[3]);
      unsigned short* sd = st16 + ((size_t)li*2+(size_t)((t+1)&1))*32768 + row*1024 + wr*16 + hf*8;
      cstore16(sd, w0, w1, w2, w3);
      if (li<3){
        unsigned short* hd = h16 + ((size_t)li*2+(size_t)(t&1))*32768 + row*1024 + wr*16 + hf*8;
        cstore16(hd, w0, w1, w2, w3);
      }
      if (t==T_-1){
        float* op = ostate + (size_t)li*BD_ + (size_t)row*D_ + wr*16 + hf*8;
        *(f32x4*)op = q0; *(f32x4*)(op+4) = q1;
      }
    }

    // ---- arrive: drain this wave's stores/atomics, sync WG, one counter bump (fire-and-forget)
    asm volatile("s_waitcnt vmcnt(0)" ::: "memory");
    __syncthreads();
    if (tid==0)
      __hip_atomic_fetch_add(prog+li*64, 1u, __ATOMIC_RELAXED, __HIP_MEMORY_SCOPE_AGENT);
  }

  // ---- tail: y[511] (li3 only; needs all li3 WGs' ystat(511) atomics)
  if (li==3){
    if (tid==0){
      while (cldu(prog+3*64) < 64u*(unsigned)T_) __builtin_amdgcn_s_sleep(1);
    }
    __syncthreads();
    const float* stY=ystat+((T_-1)&3)*64;
    float gv=SGSB[col], bv=SGSB[16+col];
    float s1=cload1(stY+r0*2), s2=cload1(stY+r0*2+1);
    float m0=s1*(1.f/1024.f);
    float rs0=rsqrtf(s2*(1.f/1024.f)-m0*m0+EPSF);
    y[(size_t)(T_-1)*BD_+(size_t)r0*D_+wr*16+col]=(pns.x-m0)*rs0*gv+bv;
    float s3=cload1(stY+r1*2), s4=cload1(stY+r1*2+1);
    float m1=s3*(1.f/1024.f);
    float rs1=rsqrtf(s4*(1.f/1024.f)-m1*m1+EPSF);
    y[(size_t)(T_-1)*BD_+(size_t)r1*D_+wr*16+col]=(pns.y-m1)*rs1*gv+bv;
  }
}

extern "C" void kernel_launch(void* const* d_in, const int* in_sizes, int n_in,
                              void* d_out, int out_size, void* d_ws, size_t ws_size,
                              hipStream_t stream){
  (void)in_sizes; (void)n_in; (void)out_size; (void)ws_size;
  const float* x   = (const float*)d_in[0];
  const float* st0 = (const float*)d_in[1];
  const float* Wf  = (const float*)d_in[2];
  const float* Uf  = (const float*)d_in[3];
  const float* bfv = (const float*)d_in[4];
  const float* Wc  = (const float*)d_in[5];
  const float* Uc  = (const float*)d_in[6];
  const float* bcv = (const float*)d_in[7];
  const float* pg  = (const float*)d_in[8];
  const float* pb  = (const float*)d_in[9];
  const float* sg  = (const float*)d_in[10];
  const float* sbv = (const float*)d_in[11];

  float* y      = (float*)d_out;
  float* ostate = y + (size_t)T_*BD_;
  char* ws = (char*)d_ws;

  (void)hipMemsetAsync(ws, 0, 8192, stream);
  hipLaunchKernelGGL(crs_prepass, dim3(8192), dim3(256), 0, stream,
                     Wf, Uf, Wc, Uc, (unsigned short*)(ws+WSO_WT));
  hipLaunchKernelGGL(crs_prep2, dim3(T_+L_), dim3(256), 0, stream,
                     x, st0, (float*)(ws+WSO_XSTAT), (unsigned short*)(ws+WSO_ST16));
  (void)hipFuncSetAttribute((const void*)crs_main, hipFuncAttributeMaxDynamicSharedMemorySize, LDS_TOTAL);
  hipLaunchKernelGGL(crs_main, dim3(NWG), dim3(TPB), LDS_TOTAL, stream,
                     x, st0, bfv, bcv, pg, pb, sg, sbv, y, ostate,
                     (const unsigned short*)(ws+WSO_WT), ws);
}

// Round 12
// 7873.110 us; speedup vs baseline: 1.5487x; 1.0400x over previous
//
#include <hip/hip_runtime.h>
#include <cstdint>
#include <cstddef>

#define T_ 512
#define B_ 32
#define D_ 1024
#define L_ 4
#define BD_ (B_*D_)
#define TPB 256
#define NWG 256
#define EPSF 1e-5f

typedef _Float16 f16x8 __attribute__((ext_vector_type(8)));
typedef float f32x4 __attribute__((ext_vector_type(4)));
typedef float f32x2 __attribute__((ext_vector_type(2)));
typedef unsigned int u32x4 __attribute__((ext_vector_type(4)));
typedef unsigned long long u64;

// workspace layout (bytes) — no-reuse streams
#define WSO_PROG   0                      // 4 layer progress counters, 256B apart
#define WSO_XSTAT  4096                   // [512][32][2] f32 = 128KB
#define WSO_HSTAT  135168                 // [3][512][32][2] f32 = 384KB
#define WSO_YSTAT  528384                 // [512][32][2] f32 = 128KB
#define WSO_ZEND   659456                 // memset end
#define WSO_WT     1048576                // fp16 weights, 32MB
#define WSO_H16    34603008               // [4][513][32][1024] fp16 streams = 128.25MB (~169MB total)

// LDS layout (bytes)
#define LDS_W     0        // 32 cols x 2048 fused-k fp16, col stride 4096, XOR-swizzled
#define LDS_DUMP  131072   // 16 tiles x 64 lanes x 16B
#define LDS_GB    147456   // li0: f32 g|b (8KB); li>0: packed fp16 (4KB)
#define LDS_MRS   155648   // 32 float2
#define LDS_NS    155904   // 32 rows x 20 floats
#define LDS_BIAS  158464
#define LDS_SGSB  158592
#define LDS_TOTAL 158720
#define NSTR 20

__device__ __forceinline__ unsigned pk2h(float a, float b){
  _Float16 ha=(_Float16)a, hb=(_Float16)b;
  return (unsigned)__builtin_bit_cast(unsigned short,ha) |
         ((unsigned)__builtin_bit_cast(unsigned short,hb)<<16);
}
__device__ __forceinline__ float cload1(const float* p){
  unsigned v=__hip_atomic_load((const unsigned*)(const void*)p,__ATOMIC_RELAXED,__HIP_MEMORY_SCOPE_AGENT);
  return __builtin_bit_cast(float,v);
}
__device__ __forceinline__ unsigned cldu(const unsigned* p){
  return __hip_atomic_load(p,__ATOMIC_RELAXED,__HIP_MEMORY_SCOPE_AGENT);
}
// 16B write-through store (2 x u64 relaxed agent atomics — reach L3; proven r4-r11)
__device__ __forceinline__ void cstore16(unsigned short* p, unsigned w0, unsigned w1, unsigned w2, unsigned w3){
  u64 lo=((u64)w1<<32)|w0, hi=((u64)w3<<32)|w2;
  __hip_atomic_store((u64*)(void*)p,     lo, __ATOMIC_RELAXED, __HIP_MEMORY_SCOPE_AGENT);
  __hip_atomic_store((u64*)(void*)(p+4), hi, __ATOMIC_RELAXED, __HIP_MEMORY_SCOPE_AGENT);
}

#define GLDX(d,vo,sb) asm volatile("global_load_dwordx4 %0, %1, %2" : "=v"(d) : "v"(vo), "s"(sb) : "memory")
#define WAITV(N) do{ asm volatile("s_waitcnt vmcnt(" #N ")" ::: "memory"); __builtin_amdgcn_sched_barrier(0); }while(0)
#define BARS do{ asm volatile("s_waitcnt lgkmcnt(0)" ::: "memory"); __builtin_amdgcn_s_barrier(); }while(0)

// per-chunk A loads — ALL plain cached (no-reuse addresses make L2 safe; 8 WGs/XCD share lines)
#define LOADC(c) do{ const int s_=(c)&3; \
  if (ISX){ \
    if ((c)<8){ \
      GLDX(pay[s_][0][0], vxA+(c)*512,    sbH); GLDX(pay[s_][0][1], vxA+(c)*512+16, sbH); \
      GLDX(pay[s_][1][0], vxB+(c)*512,    sbH); GLDX(pay[s_][1][1], vxB+(c)*512+16, sbH); \
    } else { \
      GLDX(pay[s_][0][0], voA+((c)-8)*256, sbS); GLDX(pay[s_][1][0], voB+((c)-8)*256, sbS); \
    } \
  } else { \
    if ((c)<8){ GLDX(pay[s_][0][0], voA+(c)*256, sbH); GLDX(pay[s_][1][0], voB+(c)*256, sbH); } \
    else      { GLDX(pay[s_][0][0], voA+((c)-8)*256, sbS); GLDX(pay[s_][1][0], voB+((c)-8)*256, sbS); } \
  } \
}while(0)

#define PROC(c) do{ const int s_=(c)&3; f16x8 a0,a1; \
    const int kf_=(c)*128+kq; \
    if ((c)<8){ \
      if (ISX){ \
        f32x4 xa0=__builtin_bit_cast(f32x4,pay[s_][0][0]), xa1=__builtin_bit_cast(f32x4,pay[s_][0][1]); \
        f32x4 xb0=__builtin_bit_cast(f32x4,pay[s_][1][0]), xb1=__builtin_bit_cast(f32x4,pay[s_][1][1]); \
        f32x4 g0=*(const f32x4*)(GBg32+kf_), g1=*(const f32x4*)(GBg32+kf_+4); \
        f32x4 q0=*(const f32x4*)(GBg32+1024+kf_), q1=*(const f32x4*)(GBg32+1024+kf_+4); \
        a0[0]=(_Float16)((xa0[0]*rsA+nmA)*g0[0]+q0[0]); a0[1]=(_Float16)((xa0[1]*rsA+nmA)*g0[1]+q0[1]); \
        a0[2]=(_Float16)((xa0[2]*rsA+nmA)*g0[2]+q0[2]); a0[3]=(_Float16)((xa0[3]*rsA+nmA)*g0[3]+q0[3]); \
        a0[4]=(_Float16)((xa1[0]*rsA+nmA)*g1[0]+q1[0]); a0[5]=(_Float16)((xa1[1]*rsA+nmA)*g1[1]+q1[1]); \
        a0[6]=(_Float16)((xa1[2]*rsA+nmA)*g1[2]+q1[2]); a0[7]=(_Float16)((xa1[3]*rsA+nmA)*g1[3]+q1[3]); \
        a1[0]=(_Float16)((xb0[0]*rsB+nmB)*g0[0]+q0[0]); a1[1]=(_Float16)((xb0[1]*rsB+nmB)*g0[1]+q0[1]); \
        a1[2]=(_Float16)((xb0[2]*rsB+nmB)*g0[2]+q0[2]); a1[3]=(_Float16)((xb0[3]*rsB+nmB)*g0[3]+q0[3]); \
        a1[4]=(_Float16)((xb1[0]*rsB+nmB)*g1[0]+q1[0]); a1[5]=(_Float16)((xb1[1]*rsB+nmB)*g1[1]+q1[1]); \
        a1[6]=(_Float16)((xb1[2]*rsB+nmB)*g1[2]+q1[2]); a1[7]=(_Float16)((xb1[3]*rsB+nmB)*g1[3]+q1[3]); \
      } else { \
        f16x8 g8=*(const f16x8*)(GBg16+(kf_>>1)); \
        f16x8 b8=*(const f16x8*)(GBg16+512+(kf_>>1)); \
        a0=__builtin_bit_cast(f16x8,pay[s_][0][0]); a1=__builtin_bit_cast(f16x8,pay[s_][1][0]); \
        a0=a0*rsA8+nmA8; a0=a0*g8+b8; \
        a1=a1*rsB8+nmB8; a1=a1*g8+b8; \
      } \
    } else { \
      a0=__builtin_bit_cast(f16x8,pay[s_][0][0]); a1=__builtin_bit_cast(f16x8,pay[s_][1][0]); \
    } \
    const int kb_=kf_*2; \
    f16x8 bF=*(const f16x8*)(WF + (kb_^swl)); \
    f16x8 bC=*(const f16x8*)(WC + (kb_^swl)); \
    accF0=__builtin_amdgcn_mfma_f32_16x16x32_f16(a0,bF,accF0,0,0,0); \
    accF1=__builtin_amdgcn_mfma_f32_16x16x32_f16(a1,bF,accF1,0,0,0); \
    accC0=__builtin_amdgcn_mfma_f32_16x16x32_f16(a0,bC,accC0,0,0,0); \
    accC1=__builtin_amdgcn_mfma_f32_16x16x32_f16(a1,bC,accC1,0,0,0); \
  }while(0)

#define CH(c,NW) do{ if ((c)<13) LOADC((c)+3); WAITV(NW); PROC(c); }while(0)

template<int ISX>
__device__ __forceinline__ void stage_pre(u32x4 (&pay)[4][2][2],
    u64 sbH, u64 sbS, int voA, int voB, int vxA, int vxB)
{
  LOADC(0); LOADC(1); LOADC(2);
}

template<int ISX>
__device__ __forceinline__ void chunk_run(char* smem, u32x4 (&pay)[4][2][2],
    u64 sbH, u64 sbS, int voA, int voB, int vxA, int vxB,
    int l15, int kq, float2 mrA, float2 mrB,
    f32x4& accF0, f32x4& accF1, f32x4& accC0, f32x4& accC1)
{
  const char* WF = smem + LDS_W + l15*4096;
  const char* WC = smem + LDS_W + (16+l15)*4096;
  const int swl = (l15&7)<<4;
  const float rsA = mrA.y, rsB = mrB.y;
  const float nmA = -mrA.x*rsA, nmB = -mrB.x*rsB;
  const _Float16 hrA=(_Float16)rsA, hmA=(_Float16)nmA, hrB=(_Float16)rsB, hmB=(_Float16)nmB;
  const f16x8 rsA8={hrA,hrA,hrA,hrA,hrA,hrA,hrA,hrA};
  const f16x8 nmA8={hmA,hmA,hmA,hmA,hmA,hmA,hmA,hmA};
  const f16x8 rsB8={hrB,hrB,hrB,hrB,hrB,hrB,hrB,hrB};
  const f16x8 nmB8={hmB,hmB,hmB,hmB,hmB,hmB,hmB,hmB};
  const unsigned* GBg16 = (const unsigned*)(smem+LDS_GB);
  const float* GBg32 = (const float*)(smem+LDS_GB);

  if (ISX){
    CH(0,12);CH(1,12);CH(2,12);CH(3,12);CH(4,12);CH(5,10);CH(6,8);CH(7,6);
    CH(8,6);CH(9,6);CH(10,6);CH(11,6);CH(12,6);CH(13,4);CH(14,2);CH(15,0);
  } else {
    CH(0,6);CH(1,6);CH(2,6);CH(3,6);CH(4,6);CH(5,6);CH(6,6);CH(7,6);
    CH(8,6);CH(9,6);CH(10,6);CH(11,6);CH(12,6);CH(13,4);CH(14,2);CH(15,0);
  }
}

// ---------------- pre-pass 1: fp32 (D,D) row-major -> fp16 transposed fused layout ----------------
extern "C" __global__ void __launch_bounds__(256,1) crs_prepass(
    const float* __restrict__ Wf, const float* __restrict__ Uf,
    const float* __restrict__ Wc, const float* __restrict__ Uc,
    unsigned short* __restrict__ WT)
{
  int bid = blockIdx.x;
  int kt  = bid & 15;
  int ct  = (bid>>4) & 31;
  int sel = (bid>>9) & 3;
  int i   = bid >> 11;
  int tid = threadIdx.x;
  int kq  = tid >> 5;
  int cc  = tid & 31;
  const float* sp;
  if      (sel==0) sp = Wf;
  else if (sel==1) sp = Uf;
  else if (sel==2) sp = Wc;
  else             sp = Uc;
  sp += (size_t)i * 1048576;
  int cl = ct*32 + cc;
  int k0 = kt*64 + kq*8;
  float f[8];
  #pragma unroll
  for (int e=0;e<8;++e){ f[e] = sp[(size_t)(k0+e)*1024 + cl]; }
  int cg = ((sel>>1) ? 1024 : 0) + cl;
  int ks = sel & 1;
  size_t idx = ((size_t)(i*2048 + cg)*2 + ks)*1024 + k0;
  uint4 pk;
  pk.x = pk2h(f[0], f[1]);
  pk.y = pk2h(f[2], f[3]);
  pk.z = pk2h(f[4], f[5]);
  pk.w = pk2h(f[6], f[7]);
  *(uint4*)(WT + idx) = pk;
}

// ---------------- pre-pass 2: x row-stats + initial state -> H16 slot 0 ----------------
extern "C" __global__ void __launch_bounds__(256,1) crs_prep2(
    const float* __restrict__ x, const float* __restrict__ st0,
    float* __restrict__ xstat, unsigned short* __restrict__ H16)
{
  __shared__ float2 part[256];
  int bid=blockIdx.x, tid=threadIdx.x;
  int rr=tid>>3, ss=tid&7;
  if (bid<T_){
    const float4* p4=(const float4*)(x+(size_t)bid*BD_+rr*1024+ss*128);
    float s1=0.f,s2=0.f;
    #pragma unroll 8
    for (int q=0;q<32;++q){ float4 a=p4[q]; s1+=a.x+a.y+a.z+a.w; s2+=a.x*a.x+a.y*a.y+a.z*a.z+a.w*a.w; }
    part[tid]=make_float2(s1,s2);
    __syncthreads();
    if (tid<32){
      float a1=0.f,a2=0.f;
      #pragma unroll
      for (int e=0;e<8;++e){ float2 pp=part[tid*8+e]; a1+=pp.x; a2+=pp.y; }
      xstat[bid*64+tid*2]=a1; xstat[bid*64+tid*2+1]=a2;
    }
  } else {
    int i2=bid-T_;
    const float4* p4=(const float4*)(st0+(size_t)i2*BD_+rr*1024+ss*128);
    uint4* dst=(uint4*)(H16+(size_t)i2*513*32768+rr*1024+ss*128);
    #pragma unroll
    for (int q=0;q<16;++q){
      float4 a=p4[2*q], b=p4[2*q+1];
      uint4 pk; pk.x=pk2h(a.x,a.y); pk.y=pk2h(a.z,a.w); pk.z=pk2h(b.x,b.y); pk.w=pk2h(b.z,b.w);
      dst[q]=pk;
    }
  }
}

// ---------------- main persistent kernel: dataflow + append-only state streams ----------------
extern "C" __global__ void __launch_bounds__(TPB,1) crs_main(
    const float* __restrict__ x, const float* __restrict__ st0,
    const float* __restrict__ bfv, const float* __restrict__ bcv,
    const float* __restrict__ pg, const float* __restrict__ pb,
    const float* __restrict__ sg, const float* __restrict__ sbv,
    float* __restrict__ y, float* __restrict__ ostate,
    const unsigned short* __restrict__ WT, char* __restrict__ ws)
{
  extern __shared__ char smem[];
  const int tid=threadIdx.x, w=blockIdx.x;
  const int li=w>>6, wr=w&63;
  const int lane=tid&63, v=tid>>6;        // v = k-quarter
  const int l15=lane&15, lg=(lane>>4)&3;
  const int kq = v*32 + lg*8;
  const int col=lane&15, rp=lane>>4;
  const int r0=v*8+rp, r1=v*8+4+rp;
  const int sseg=tid&7;

  unsigned* prog=(unsigned*)(ws+WSO_PROG);
  float* hstat=(float*)(ws+WSO_HSTAT);
  float* ystat=(float*)(ws+WSO_YSTAT);
  float* xstat=(float*)(ws+WSO_XSTAT);
  unsigned short* H16=(unsigned short*)(ws+WSO_H16);
  float* NSf=(float*)(smem+LDS_NS);
  float* BIAS=(float*)(smem+LDS_BIAS);
  float* SGSB=(float*)(smem+LDS_SGSB);

  // ---- one-time init: weights -> LDS (swizzled)
  {
    int lc=tid>>3;
    int cgl=(lc>>4)*1024 + wr*16 + (lc&15);
    const unsigned short* src=WT + ((size_t)li*2048+cgl)*2048;
    char* dcol = smem + LDS_W + lc*4096;
    int sw2=(lc&7)<<4;
    #pragma unroll
    for (int n=0;n<32;++n){
      int q=sseg+n*8;
      uint4 d=*(const uint4*)(src+q*8);
      *(uint4*)(dcol + ((q*16)^sw2)) = d;
    }
  }
  if (li==0){
    float* g32=(float*)(smem+LDS_GB);
    for (int k=tid;k<1024;k+=TPB){ g32[k]=pg[k]; g32[1024+k]=pb[k]; }
  } else {
    unsigned* g16=(unsigned*)(smem+LDS_GB);
    for (int k=tid;k<512;k+=TPB){
      g16[k]    =pk2h(pg[li*1024+2*k], pg[li*1024+2*k+1]);
      g16[512+k]=pk2h(pb[li*1024+2*k], pb[li*1024+2*k+1]);
    }
  }
  if (tid<16) BIAS[tid]=bfv[li*1024+wr*16+tid];
  else if (tid<32) BIAS[tid]=bcv[li*1024+wr*16+(tid-16)];
  if (li==3){
    if (tid<16) SGSB[tid]=sg[wr*16+tid];
    else if (tid<32) SGSB[tid]=sbv[wr*16+(tid-16)];
  }
  f32x2 sreg, pns={0.f,0.f};
  sreg.x = st0[(size_t)li*BD_ + (size_t)r0*D_ + wr*16+col];
  sreg.y = st0[(size_t)li*BD_ + (size_t)r1*D_ + wr*16+col];
  __syncthreads();

  for (int t=0; t<T_; ++t){
    // ---- dataflow wait: own-layer state(t) complete, upstream h(t) complete
    if (tid==0){
      const unsigned ow=64u*(unsigned)t;
      const unsigned uw=64u*(unsigned)(t+1);
      for(;;){
        bool ok = (cldu(prog+li*64) >= ow);
        if (ok && li>0) ok = (cldu(prog+(li-1)*64) >= uw);
        if (ok) break;
        __builtin_amdgcn_s_sleep(1);
      }
    }
    __syncthreads();

    // ---- front-matter
    if (li==3 && t>=1){
      const float* stY=ystat+(size_t)(t-1)*64;
      float gv=SGSB[col], bv=SGSB[16+col];
      float s1=cload1(stY+r0*2), s2=cload1(stY+r0*2+1);
      float m0=s1*(1.f/1024.f);
      float rs0=rsqrtf(s2*(1.f/1024.f)-m0*m0+EPSF);
      y[(size_t)(t-1)*BD_+(size_t)r0*D_+wr*16+col]=(pns.x-m0)*rs0*gv+bv;
      float s3=cload1(stY+r1*2), s4=cload1(stY+r1*2+1);
      float m1=s3*(1.f/1024.f);
      float rs1=rsqrtf(s4*(1.f/1024.f)-m1*m1+EPSF);
      y[(size_t)(t-1)*BD_+(size_t)r1*D_+wr*16+col]=(pns.y-m1)*rs1*gv+bv;
    }
    if (v==0 && tid<32){
      float s1,s2;
      if (li==0){ s1=xstat[t*64+tid*2]; s2=xstat[t*64+tid*2+1]; }
      else { const float* hs=hstat+((size_t)(li-1)*512+t)*64; s1=cload1(hs+tid*2); s2=cload1(hs+tid*2+1); }
      float m=s1*(1.f/1024.f);
      ((float2*)(smem+LDS_MRS))[tid]=make_float2(m, rsqrtf(s2*(1.f/1024.f)-m*m+EPSF));
    }
    asm volatile("s_waitcnt vmcnt(0)" ::: "memory");

    // ---- A bases: h-half = upstream stream slot t+1 (or x); state-half = own stream slot t
    u64 sbH = (li==0)? (u64)(uintptr_t)(x + (size_t)t*BD_)
                     : (u64)(uintptr_t)(H16 + ((size_t)(li-1)*513 + (size_t)(t+1))*32768);
    u64 sbS = (u64)(uintptr_t)(H16 + ((size_t)li*513 + (size_t)t)*32768);
    const int voA = l15*2048 + kq*2, voB = voA + 32768;
    const int vxA = l15*4096 + kq*4, vxB = vxA + 65536;
    u32x4 pay[4][2][2];
    if (li==0) stage_pre<1>(pay, sbH, sbS, voA, voB, vxA, vxB);
    else       stage_pre<0>(pay, sbH, sbS, voA, voB, vxA, vxB);
    BARS;
    float2 mrA=((const float2*)(smem+LDS_MRS))[l15];
    float2 mrB=((const float2*)(smem+LDS_MRS))[16+l15];

    f32x4 accF0={0,0,0,0}, accF1={0,0,0,0}, accC0={0,0,0,0}, accC1={0,0,0,0};
    if (li==0) chunk_run<1>(smem, pay, sbH, sbS, voA, voB, vxA, vxB, l15, kq, mrA, mrB, accF0, accF1, accC0, accC1);
    else       chunk_run<0>(smem, pay, sbH, sbS, voA, voB, vxA, vxB, l15, kq, mrA, mrB, accF0, accF1, accC0, accC1);

    *(f32x4*)(smem+LDS_DUMP + (((v*4+0)*64+lane)<<4)) = accF0;
    *(f32x4*)(smem+LDS_DUMP + (((v*4+1)*64+lane)<<4)) = accF1;
    *(f32x4*)(smem+LDS_DUMP + (((v*4+2)*64+lane)<<4)) = accC0;
    *(f32x4*)(smem+LDS_DUMP + (((v*4+3)*64+lane)<<4)) = accC1;
    BARS;

    {
      const int rtl = v>>1;
      const int lg20 = (v&1)*2, lg21 = (v&1)*2+1;
      float fF0=0.f,fF1=0.f,fC0=0.f,fC1=0.f;
      #pragma unroll
      for (int v2=0;v2<4;++v2){
        const char* db = smem+LDS_DUMP + v2*4096;
        fF0 += *(const float*)(db + (((0+rtl)*64 + lg20*16+col)<<4) + rp*4);
        fF1 += *(const float*)(db + (((0+rtl)*64 + lg21*16+col)<<4) + rp*4);
        fC0 += *(const float*)(db + (((2+rtl)*64 + lg20*16+col)<<4) + rp*4);
        fC1 += *(const float*)(db + (((2+rtl)*64 + lg21*16+col)<<4) + rp*4);
      }
      float bfc=BIAS[col], bcc=BIAS[16+col];
      float preF0=fminf(fmaxf(fF0+bfc,-30.f),30.f);
      float preC0=fminf(fmaxf(fC0+bcc,-30.f),30.f);
      float preF1=fminf(fmaxf(fF1+bfc,-30.f),30.f);
      float preC1=fminf(fmaxf(fC1+bcc,-30.f),30.f);
      float fg0=1.f/(1.f+__expf(-preF0)), e0=__expf(-2.f*preC0);
      float cd0=(1.f-e0)/(1.f+e0);
      float fg1=1.f/(1.f+__expf(-preF1)), e1=__expf(-2.f*preC1);
      float cd1=(1.f-e1)/(1.f+e1);
      float ns0=fg0*sreg.x+(1.f-fg0)*cd0;
      float ns1=fg1*sreg.y+(1.f-fg1)*cd1;
      sreg.x=ns0; sreg.y=ns1;
      if (li==3){ pns.x=ns0; pns.y=ns1; }
      float a1=ns0, a2=ns0*ns0, a3=ns1, a4=ns1*ns1;
      #pragma unroll
      for (int m=1;m<16;m<<=1){
        a1+=__shfl_xor(a1,m); a2+=__shfl_xor(a2,m);
        a3+=__shfl_xor(a3,m); a4+=__shfl_xor(a4,m);
      }
      float* stadd=(li<3)? (hstat+((size_t)li*512+t)*64) : (ystat+(size_t)t*64);
      if (col==0){
        atomicAdd(stadd+r0*2,   a1); atomicAdd(stadd+r0*2+1, a2);
        atomicAdd(stadd+r1*2,   a3); atomicAdd(stadd+r1*2+1, a4);
      }
      NSf[r0*NSTR+col]=ns0;
      NSf[r1*NSTR+col]=ns1;
    }
    BARS;

    if (lane<16){
      int row = v*8 + (lane>>1), hf = lane&1;
      const float* nr = NSf + row*NSTR + hf*8;
      f32x4 q0 = *(const f32x4*)nr, q1 = *(const f32x4*)(nr+4);
      unsigned w0=pk2h(q0[0],q0[1]), w1=pk2h(q0[2],q0[3]);
      unsigned w2=pk2h(q1[0],q1[1]), w3=pk2h(q1[2],q1[3]);
      unsigned short* sd = H16 + ((size_t)li*513 + (size_t)(t+1))*32768 + row*1024 + wr*16 + hf*8;
      cstore16(sd, w0, w1, w2, w3);
      if (t==T_-1){
        float* op = ostate + (size_t)li*BD_ + (size_t)row*D_ + wr*16 + hf*8;
        *(f32x4*)op = q0; *(f32x4*)(op+4) = q1;
      }
    }

    // ---- arrive: drain stores/atomics, sync WG, bump layer counter
    asm volatile("s_waitcnt vmcnt(0)" ::: "memory");
    __syncthreads();
    if (tid==0)
      __hip_atomic_fetch_add(prog+li*64, 1u, __ATOMIC_RELAXED, __HIP_MEMORY_SCOPE_AGENT);
  }

  // ---- tail: y[511]
  if (li==3){
    if (tid==0){
      while (cldu(prog+3*64) < 64u*(unsigned)T_) __builtin_amdgcn_s_sleep(1);
    }
    __syncthreads();
    const float* stY=ystat+(size_t)(T_-1)*64;
    float gv=SGSB[col], bv=SGSB[16+col];
    float s1=cload1(stY+r0*2), s2=cload1(stY+r0*2+1);
    float m0=s1*(1.f/1024.f);
    float rs0=rsqrtf(s2*(1.f/1024.f)-m0*m0+EPSF);
    y[(size_t)(T_-1)*BD_+(size_t)r0*D_+wr*16+col]=(pns.x-m0)*rs0*gv+bv;
    float s3=cload1(stY+r1*2), s4=cload1(stY+r1*2+1);
    float m1=s3*(1.f/1024.f);
    float rs1=rsqrtf(s4*(1.f/1024.f)-m1*m1+EPSF);
    y[(size_t)(T_-1)*BD_+(size_t)r1*D_+wr*16+col]=(pns.y-m1)*rs1*gv+bv;
  }
}

extern "C" void kernel_launch(void* const* d_in, const int* in_sizes, int n_in,
                              void* d_out, int out_size, void* d_ws, size_t ws_size,
                              hipStream_t stream){
  (void)in_sizes; (void)n_in; (void)out_size; (void)ws_size;
  const float* x   = (const float*)d_in[0];
  const float* st0 = (const float*)d_in[1];
  const float* Wf  = (const float*)d_in[2];
  const float* Uf  = (const float*)d_in[3];
  const float* bfv = (const float*)d_in[4];
  const float* Wc  = (const float*)d_in[5];
  const float* Uc  = (const float*)d_in[6];
  const float* bcv = (const float*)d_in[7];
  const float* pg  = (const float*)d_in[8];
  const float* pb  = (const float*)d_in[9];
  const float* sg  = (const float*)d_in[10];
  const float* sbv = (const float*)d_in[11];

  float* y      = (float*)d_out;
  float* ostate = y + (size_t)T_*BD_;
  char* ws = (char*)d_ws;

  (void)hipMemsetAsync(ws, 0, WSO_ZEND, stream);
  hipLaunchKernelGGL(crs_prepass, dim3(8192), dim3(256), 0, stream,
                     Wf, Uf, Wc, Uc, (unsigned short*)(ws+WSO_WT));
  hipLaunchKernelGGL(crs_prep2, dim3(T_+L_), dim3(256), 0, stream,
                     x, st0, (float*)(ws+WSO_XSTAT), (unsigned short*)(ws+WSO_H16));
  (void)hipFuncSetAttribute((const void*)crs_main, hipFuncAttributeMaxDynamicSharedMemorySize, LDS_TOTAL);
  hipLaunchKernelGGL(crs_main, dim3(NWG), dim3(TPB), LDS_TOTAL, stream,
                     x, st0, bfv, bcv, pg, pb, sg, sbv, y, ostate,
                     (const unsigned short*)(ws+WSO_WT), ws);
}